// Round 2
// baseline (3198.052 us; speedup 1.0000x reference)
//
#include <hip/hip_runtime.h>
#include <hip/hip_bf16.h>

#define BN_INV 0.99999500003749968f  // 1/sqrt(1+1e-5)

// dims: B=4, 64x64 -> 128x128, C=128, CM=64, OUT=128, R=32, K_UP=5 (25 taps)
// Output dtype: FLOAT32 (reference computes fp32 end-to-end).

// ---------------- weight repack: OIHW -> [tap][cin][opad], fold bn scale ----
__global__ __launch_bounds__(256) void k_repack(
    const float* __restrict__ w, const float* __restrict__ g,
    float* __restrict__ out, int Cout, int Cin, int OPAD) {
  int idx = blockIdx.x * 256 + threadIdx.x;
  int total = 9 * Cin * OPAD;
  if (idx >= total) return;
  int o = idx % OPAD;
  int c = (idx / OPAD) % Cin;
  int tap = idx / (OPAD * Cin);
  float v = 0.f;
  if (o < Cout) v = w[(o * Cin + c) * 9 + tap] * g[o] * BN_INV;
  out[idx] = v;
}

// ---------------- t1 = relu(bn(conv1x1(xh, w1)))  (64ch out, 64x64) ---------
__global__ __launch_bounds__(256) void k_t1(
    const float* __restrict__ xh, const float* __restrict__ w1,
    const float* __restrict__ g, const float* __restrict__ bb,
    float* __restrict__ t1) {
  int t = threadIdx.x;
  int o = t & 63, ps = t >> 6;
  int p0 = blockIdx.x * 16 + ps * 4;  // over B*4096
  const float* ip = xh + (size_t)p0 * 128;
  const float* wp = w1 + o * 128;
  float a0 = 0, a1 = 0, a2 = 0, a3 = 0;
  for (int c = 0; c < 128; ++c) {
    float w = wp[c];
    a0 += w * ip[c];       a1 += w * ip[128 + c];
    a2 += w * ip[256 + c]; a3 += w * ip[384 + c];
  }
  float sc = g[o] * BN_INV, be = bb[o];
  t1[(size_t)(p0 + 0) * 64 + o] = fmaxf(a0 * sc + be, 0.f);
  t1[(size_t)(p0 + 1) * 64 + o] = fmaxf(a1 * sc + be, 0.f);
  t1[(size_t)(p0 + 2) * 64 + o] = fmaxf(a2 * sc + be, 0.f);
  t1[(size_t)(p0 + 3) * 64 + o] = fmaxf(a3 * sc + be, 0.f);
}

// ---------------- bilinear upsample 64->128 (align corners), NHWC -----------
template <int CH>
__global__ __launch_bounds__(256) void k_up(const float* __restrict__ in,
                                            float* __restrict__ out) {
  int t = threadIdx.x;
  int c = t % CH;
  int sub = t / CH;
  constexpr int PPB = 256 / CH;
  int g = blockIdx.x * PPB + sub;  // over B*16384
  int b = g >> 14;
  int pp = g & 16383;
  int oy = pp >> 7, ox = pp & 127;
  const float S = 63.0f / 127.0f;
  float fy = oy * S, fx = ox * S;
  int y0 = (int)fy, x0 = (int)fx;
  int y1 = min(y0 + 1, 63), x1 = min(x0 + 1, 63);
  float wy = fy - y0, wx = fx - x0;
  const float* base = in + (size_t)b * 4096 * CH;
  float v00 = base[(y0 * 64 + x0) * CH + c];
  float v01 = base[(y0 * 64 + x1) * CH + c];
  float v10 = base[(y1 * 64 + x0) * CH + c];
  float v11 = base[(y1 * 64 + x1) * CH + c];
  float top = v00 * (1.f - wx) + v01 * wx;
  float bot = v10 * (1.f - wx) + v11 * wx;
  out[(size_t)g * 128 + c] = top * (1.f - wy) + bot * wy;
}

// ---------------- SE: channel mean of xl ------------------------------------
__global__ __launch_bounds__(256) void k_semean(const float* __restrict__ xl,
                                                float* __restrict__ gmean) {
  int bid = blockIdx.x;  // B*64
  int b = bid >> 6, chunk = bid & 63;
  int t = threadIdx.x;
  int c = t & 127, sub = t >> 7;
  float s = 0.f;
  const float* base = xl + ((size_t)b * 16384 + chunk * 256) * 128;
  for (int p = sub; p < 256; p += 2) s += base[(size_t)p * 128 + c];
  __shared__ float lds[256];
  lds[t] = s;
  __syncthreads();
  if (t < 128) atomicAdd(&gmean[b * 128 + t], lds[t] + lds[t + 128]);
}

// ---------------- SE MLP + sigmoid + build per-batch effective w2 -----------
__global__ __launch_bounds__(128) void k_semlp(
    const float* __restrict__ gmean, const float* __restrict__ wf1,
    const float* __restrict__ bf1, const float* __restrict__ wf2,
    const float* __restrict__ bf2, const float* __restrict__ w2,
    float* __restrict__ weff) {
  int b = blockIdx.x;
  int t = threadIdx.x;  // 128
  __shared__ float m[128], hid[32], sg[128];
  m[t] = gmean[b * 128 + t] * (1.0f / 16384.0f);
  __syncthreads();
  if (t < 32) {
    float a = 0.f;
    for (int c = 0; c < 128; ++c) a += wf1[t * 128 + c] * m[c];
    hid[t] = fmaxf(a + bf1[t], 0.f);
  }
  __syncthreads();
  {
    float a = 0.f;
    for (int r = 0; r < 32; ++r) a += wf2[t * 32 + r] * hid[r];
    a += bf2[t];
    sg[t] = 1.f / (1.f + expf(-a));
  }
  __syncthreads();
  for (int o = 0; o < 64; ++o) {
    weff[((size_t)b * 64 + o) * 128 + t] =
        w2[o * 256 + t] * sg[t] + w2[o * 256 + 128 + t];
  }
}

// ---------------- x2 = relu(bn(weff_b . xl)) -> xcat ch 64..127 --------------
__global__ __launch_bounds__(256) void k_x2(
    const float* __restrict__ xl, const float* __restrict__ weff,
    const float* __restrict__ g, const float* __restrict__ bb,
    float* __restrict__ xcat) {
  int t = threadIdx.x;
  int o = t & 63, ps = t >> 6;
  int p0 = blockIdx.x * 16 + ps * 4;  // over B*16384
  int b = p0 >> 14;
  const float* ip = xl + (size_t)p0 * 128;
  const float* wp = weff + ((size_t)b * 64 + o) * 128;
  float a0 = 0, a1 = 0, a2 = 0, a3 = 0;
  for (int c = 0; c < 128; ++c) {
    float w = wp[c];
    a0 += w * ip[c];       a1 += w * ip[128 + c];
    a2 += w * ip[256 + c]; a3 += w * ip[384 + c];
  }
  float sc = g[o] * BN_INV, be = bb[o];
  xcat[(size_t)(p0 + 0) * 128 + 64 + o] = fmaxf(a0 * sc + be, 0.f);
  xcat[(size_t)(p0 + 1) * 128 + 64 + o] = fmaxf(a1 * sc + be, 0.f);
  xcat[(size_t)(p0 + 2) * 128 + 64 + o] = fmaxf(a2 * sc + be, 0.f);
  xcat[(size_t)(p0 + 3) * 128 + 64 + o] = fmaxf(a3 * sc + be, 0.f);
}

// ---------------- we conv 3x3, Cin=128 -> 25 (pad32), 128x128, bn (no relu) -
__global__ __launch_bounds__(256) void k_weconv(
    const float* __restrict__ xcat, const float* __restrict__ wer,
    const float* __restrict__ web, float* __restrict__ wk) {
  int t = threadIdx.x;
  int o = t & 31, psub = t >> 5;  // 8 groups x 4 pixels = 32 px/block
  int pixbase = blockIdx.x * 32;
  int b = pixbase >> 14;
  int pp = pixbase & 16383;
  int y = pp >> 7;
  int xb = (pp & 127) + psub * 4;
  float acc[4] = {0.f, 0.f, 0.f, 0.f};
  bool interior = (xb >= 1) && (xb + 4 <= 127);
  for (int ky = 0; ky < 3; ++ky) {
    int row = y + ky - 1;
    if ((unsigned)row >= 128u) continue;
    const float* rbase = xcat + (((size_t)b << 14) + (row << 7)) * 128;
    const float* wp = wer + (ky * 3 * 128) * 32 + o;
    if (interior) {
      const float* q = rbase + (size_t)(xb - 1) * 128;
      for (int c = 0; c < 128; ++c) {
        float v0 = q[c], v1 = q[128 + c], v2 = q[256 + c];
        float v3 = q[384 + c], v4 = q[512 + c], v5 = q[640 + c];
        float w0 = wp[c * 32], w1 = wp[(128 + c) * 32], w2 = wp[(256 + c) * 32];
        acc[0] += w0 * v0 + w1 * v1 + w2 * v2;
        acc[1] += w0 * v1 + w1 * v2 + w2 * v3;
        acc[2] += w0 * v2 + w1 * v3 + w2 * v4;
        acc[3] += w0 * v3 + w1 * v4 + w2 * v5;
      }
    } else {
      for (int c = 0; c < 128; ++c) {
        float v[6];
#pragma unroll
        for (int k = 0; k < 6; ++k) {
          int col = xb - 1 + k;
          int cc = min(max(col, 0), 127);
          float vv = rbase[(size_t)cc * 128 + c];
          v[k] = ((unsigned)col < 128u) ? vv : 0.f;
        }
        float w0 = wp[c * 32], w1 = wp[(128 + c) * 32], w2 = wp[(256 + c) * 32];
        acc[0] += w0 * v[0] + w1 * v[1] + w2 * v[2];
        acc[1] += w0 * v[1] + w1 * v[2] + w2 * v[3];
        acc[2] += w0 * v[2] + w1 * v[3] + w2 * v[4];
        acc[3] += w0 * v[3] + w1 * v[4] + w2 * v[5];
      }
    }
  }
  if (o < 25) {
#pragma unroll
    for (int i = 0; i < 4; ++i)
      wk[(size_t)(pixbase + psub * 4 + i) * 25 + o] = acc[i] + web[o];
  }
}

// ---------------- softmax over 25 channels ----------------------------------
__global__ __launch_bounds__(256) void k_softmax25(float* __restrict__ wk) {
  int g = blockIdx.x * 256 + threadIdx.x;  // B*16384
  float* p = wk + (size_t)g * 25;
  float mx = p[0];
#pragma unroll
  for (int i = 1; i < 25; ++i) mx = fmaxf(mx, p[i]);
  float e[25];
  float s = 0.f;
#pragma unroll
  for (int i = 0; i < 25; ++i) {
    e[i] = expf(p[i] - mx);
    s += e[i];
  }
  float inv = 1.f / s;
#pragma unroll
  for (int i = 0; i < 25; ++i) p[i] = e[i] * inv;
}

// ---------------- wr conv 3x3, 128->128, 64x64, bn+relu ---------------------
__global__ __launch_bounds__(256) void k_wrconv(
    const float* __restrict__ xh, const float* __restrict__ wrr,
    const float* __restrict__ bb, float* __restrict__ xr) {
  int t = threadIdx.x;
  int o = t & 127;
  int psub = t >> 7;  // 2 groups x 4 pixels = 8 px/block
  int pixbase = blockIdx.x * 8;  // over B*4096
  int b = pixbase >> 12;
  int pp = pixbase & 4095;
  int y = pp >> 6;
  int xb = (pp & 63) + psub * 4;
  float acc[4] = {0.f, 0.f, 0.f, 0.f};
  bool interior = (xb >= 1) && (xb + 4 <= 63);
  for (int ky = 0; ky < 3; ++ky) {
    int row = y + ky - 1;
    if ((unsigned)row >= 64u) continue;
    const float* rbase = xh + (((size_t)b << 12) + (row << 6)) * 128;
    const float* wp = wrr + (ky * 3 * 128) * 128 + o;
    if (interior) {
      const float* q = rbase + (size_t)(xb - 1) * 128;
      for (int c = 0; c < 128; ++c) {
        float v0 = q[c], v1 = q[128 + c], v2 = q[256 + c];
        float v3 = q[384 + c], v4 = q[512 + c], v5 = q[640 + c];
        float w0 = wp[c * 128], w1 = wp[(128 + c) * 128], w2 = wp[(256 + c) * 128];
        acc[0] += w0 * v0 + w1 * v1 + w2 * v2;
        acc[1] += w0 * v1 + w1 * v2 + w2 * v3;
        acc[2] += w0 * v2 + w1 * v3 + w2 * v4;
        acc[3] += w0 * v3 + w1 * v4 + w2 * v5;
      }
    } else {
      for (int c = 0; c < 128; ++c) {
        float v[6];
#pragma unroll
        for (int k = 0; k < 6; ++k) {
          int col = xb - 1 + k;
          int cc = min(max(col, 0), 63);
          float vv = rbase[(size_t)cc * 128 + c];
          v[k] = ((unsigned)col < 64u) ? vv : 0.f;
        }
        float w0 = wp[c * 128], w1 = wp[(128 + c) * 128], w2 = wp[(256 + c) * 128];
        acc[0] += w0 * v[0] + w1 * v[1] + w2 * v[2];
        acc[1] += w0 * v[1] + w1 * v[2] + w2 * v[3];
        acc[2] += w0 * v[2] + w1 * v[3] + w2 * v[4];
        acc[3] += w0 * v[3] + w1 * v[4] + w2 * v[5];
      }
    }
  }
  float be = bb[o];
  int gp0 = pixbase + psub * 4;
#pragma unroll
  for (int i = 0; i < 4; ++i)
    xr[(size_t)(gp0 + i) * 128 + o] = fmaxf(acc[i] + be, 0.f);
}

// ---------------- CARAFE reassembly -----------------------------------------
__global__ __launch_bounds__(256) void k_carafe(const float* __restrict__ xup,
                                                const float* __restrict__ wk,
                                                float* __restrict__ X) {
  int t = threadIdx.x;
  int c = t & 127;
  int sub = t >> 7;
  int g = blockIdx.x * 2 + sub;  // over B*16384
  int b = g >> 14, pp = g & 16383;
  int y = pp >> 7, x = pp & 127;
  __shared__ float wl[2][25];
  if ((t & 127) < 25) wl[sub][t & 127] = wk[(size_t)g * 25 + (t & 127)];
  __syncthreads();
  float acc = 0.f;
  const float* base = xup + ((size_t)b << 14) * 128;
#pragma unroll
  for (int i = 0; i < 5; ++i) {
    int row = y + 2 * i - 4;
    if ((unsigned)row >= 128u) continue;
#pragma unroll
    for (int jj = 0; jj < 5; ++jj) {
      int col = x + 2 * jj - 4;
      if ((unsigned)col >= 128u) continue;
      acc += wl[sub][i * 5 + jj] * base[((size_t)(row << 7) + col) * 128 + c];
    }
  }
  X[(size_t)g * 128 + c] = acc;
}

// ---------------- wo1 conv 3x3, Cin=256 (X | xl) -> 128, 128x128, bn+relu ---
__global__ __launch_bounds__(256) void k_wo1conv(
    const float* __restrict__ Xb, const float* __restrict__ xl,
    const float* __restrict__ wrr, const float* __restrict__ bb,
    float* __restrict__ y1) {
  int t = threadIdx.x;
  int o = t & 127;
  int psub = t >> 7;  // 2 groups x 8 pixels = 16 px/block
  int pixbase = blockIdx.x * 16;  // over B*16384
  int b = pixbase >> 14;
  int pp = pixbase & 16383;
  int y = pp >> 7;
  int xb = (pp & 127) + psub * 8;
  float acc[8] = {0.f, 0.f, 0.f, 0.f, 0.f, 0.f, 0.f, 0.f};
  bool interior = (xb >= 1) && (xb + 8 <= 127);
  for (int ky = 0; ky < 3; ++ky) {
    int row = y + ky - 1;
    if ((unsigned)row >= 128u) continue;
    size_t rbo = (((size_t)b << 14) + (row << 7)) * 128;
    for (int half = 0; half < 2; ++half) {
      const float* rbase = (half == 0 ? Xb : xl) + rbo;
      const float* wp = wrr + ((ky * 3) * 256 + half * 128) * 128 + o;
      if (interior) {
        const float* q = rbase + (size_t)(xb - 1) * 128;
        for (int c = 0; c < 128; ++c) {
          float v[10];
#pragma unroll
          for (int k = 0; k < 10; ++k) v[k] = q[(size_t)k * 128 + c];
          float w0 = wp[c * 128], w1 = wp[(256 + c) * 128], w2 = wp[(512 + c) * 128];
#pragma unroll
          for (int i = 0; i < 8; ++i)
            acc[i] += w0 * v[i] + w1 * v[i + 1] + w2 * v[i + 2];
        }
      } else {
        for (int c = 0; c < 128; ++c) {
          float v[10];
#pragma unroll
          for (int k = 0; k < 10; ++k) {
            int col = xb - 1 + k;
            int cc = min(max(col, 0), 127);
            float vv = rbase[(size_t)cc * 128 + c];
            v[k] = ((unsigned)col < 128u) ? vv : 0.f;
          }
          float w0 = wp[c * 128], w1 = wp[(256 + c) * 128], w2 = wp[(512 + c) * 128];
#pragma unroll
          for (int i = 0; i < 8; ++i)
            acc[i] += w0 * v[i] + w1 * v[i + 1] + w2 * v[i + 2];
        }
      }
    }
  }
  float be = bb[o];
#pragma unroll
  for (int i = 0; i < 8; ++i) {
    int gp = pixbase + psub * 8 + i;
    y1[(size_t)gp * 128 + o] = fmaxf(acc[i] + be, 0.f);
  }
}

// ---------------- wo2 1x1 conv + bn + relu, write NCHW fp32 ------------------
__global__ __launch_bounds__(256) void k_wo2(
    const float* __restrict__ y1, const float* __restrict__ w,
    const float* __restrict__ g, const float* __restrict__ bb,
    float* __restrict__ out) {
  int bid = blockIdx.x;  // B*128*2
  int xh_ = bid & 1;
  int y = (bid >> 1) & 127;
  int b = bid >> 8;
  int t = threadIdx.x;
  __shared__ float lds[128 * 65];
  const float* src = y1 + (((size_t)b << 14) + (y << 7) + (xh_ << 6)) * 128;
  for (int it = 0; it < 32; ++it) {
    int idx = it * 256 + t;
    int c = idx & 127, x = idx >> 7;
    lds[c * 65 + x] = src[(size_t)x * 128 + c];
  }
  __syncthreads();
  int x = t & 63, oq = t >> 6;
  size_t obase = (((size_t)b * 128) * 128 + y) * 128 + (xh_ << 6) + x;
  for (int o = oq * 32; o < oq * 32 + 32; ++o) {
    const float* wp = w + o * 128;
    float a0 = 0, a1 = 0;
    for (int c = 0; c < 128; c += 2) {
      a0 += lds[c * 65 + x] * wp[c];
      a1 += lds[(c + 1) * 65 + x] * wp[c + 1];
    }
    float r = fmaxf((a0 + a1) * (g[o] * BN_INV) + bb[o], 0.f);
    out[obase + (size_t)o * 16384] = r;
  }
}

extern "C" void kernel_launch(void* const* d_in, const int* in_sizes, int n_in,
                              void* d_out, int out_size, void* d_ws,
                              size_t ws_size, hipStream_t stream) {
  const float* x_h  = (const float*)d_in[0];
  const float* x_l  = (const float*)d_in[1];
  const float* wr   = (const float*)d_in[2];
  const float* wr_g = (const float*)d_in[3];
  const float* wr_b = (const float*)d_in[4];
  const float* w1   = (const float*)d_in[5];
  const float* w1_g = (const float*)d_in[6];
  const float* w1_b = (const float*)d_in[7];
  const float* w2   = (const float*)d_in[8];
  const float* w2_g = (const float*)d_in[9];
  const float* w2_b = (const float*)d_in[10];
  const float* we   = (const float*)d_in[11];
  const float* we_g = (const float*)d_in[12];
  const float* we_b = (const float*)d_in[13];
  const float* wf1  = (const float*)d_in[14];
  const float* bf1  = (const float*)d_in[15];
  const float* wf2  = (const float*)d_in[16];
  const float* bf2  = (const float*)d_in[17];
  const float* wo1  = (const float*)d_in[18];
  const float* wo1_g= (const float*)d_in[19];
  const float* wo1_b= (const float*)d_in[20];
  const float* wo2  = (const float*)d_in[21];
  const float* wo2_g= (const float*)d_in[22];
  const float* wo2_b= (const float*)d_in[23];
  float* out = (float*)d_out;

  float* ws    = (float*)d_ws;
  float* xcat  = ws;                 // 8,388,608   (x1|x2; later reused for X)
  float* wkb   = xcat + 8388608;     // 1,638,400   (Wk)
  float* xr    = wkb + 1638400;      // 2,097,152
  float* xup   = xr + 2097152;       // 8,388,608   (later reused for y1)
  float* t1    = xup + 8388608;      // 1,048,576
  float* gmean = t1 + 1048576;       // 512
  float* weff  = gmean + 512;        // 32,768
  float* wr_r  = weff + 32768;       // 147,456
  float* we_r  = wr_r + 147456;      // 36,864
  float* wo1_r = we_r + 36864;       // 294,912

  hipMemsetAsync(gmean, 0, 512 * sizeof(float), stream);

  k_repack<<<576, 256, 0, stream>>>(wr, wr_g, wr_r, 128, 128, 128);
  k_repack<<<144, 256, 0, stream>>>(we, we_g, we_r, 25, 128, 32);
  k_repack<<<1152, 256, 0, stream>>>(wo1, wo1_g, wo1_r, 128, 256, 128);

  k_t1<<<1024, 256, 0, stream>>>(x_h, w1, w1_g, w1_b, t1);
  k_up<64><<<16384, 256, 0, stream>>>(t1, xcat);          // x1 -> ch 0..63
  k_semean<<<256, 256, 0, stream>>>(x_l, gmean);
  k_semlp<<<4, 128, 0, stream>>>(gmean, wf1, bf1, wf2, bf2, w2, weff);
  k_x2<<<4096, 256, 0, stream>>>(x_l, weff, w2_g, w2_b, xcat);  // ch 64..127
  k_weconv<<<2048, 256, 0, stream>>>(xcat, we_r, we_b, wkb);
  k_softmax25<<<256, 256, 0, stream>>>(wkb);
  k_wrconv<<<2048, 256, 0, stream>>>(x_h, wr_r, wr_b, xr);
  k_up<128><<<32768, 256, 0, stream>>>(xr, xup);
  k_carafe<<<32768, 256, 0, stream>>>(xup, wkb, xcat);    // X overwrites xcat
  k_wo1conv<<<4096, 256, 0, stream>>>(xcat, x_l, wo1_r, wo1_b, xup);  // y1
  k_wo2<<<1024, 256, 0, stream>>>(xup, wo2, wo2_g, wo2_b, out);
}

// Round 3
// 1379.075 us; speedup vs baseline: 2.3190x; 2.3190x over previous
//
#include <hip/hip_runtime.h>
#include <hip/hip_bf16.h>

#define BN_INV 0.99999500003749968f  // 1/sqrt(1+1e-5)

typedef __attribute__((ext_vector_type(8))) short bf16x8;
typedef __attribute__((ext_vector_type(4))) float f32x4;
typedef __attribute__((ext_vector_type(8))) unsigned short ushort8;

__device__ inline unsigned short f2bf(float f) {
  union { float f; unsigned int u; } v;
  v.f = f;
  unsigned int r = v.u + 0x7FFFu + ((v.u >> 16) & 1u);
  return (unsigned short)(r >> 16);
}

// ---------------- weight repack: OIHW -> [tap][cin][opad], fold bn scale ----
__global__ __launch_bounds__(256) void k_repack(
    const float* __restrict__ w, const float* __restrict__ g,
    float* __restrict__ out, int Cout, int Cin, int OPAD) {
  int idx = blockIdx.x * 256 + threadIdx.x;
  int total = 9 * Cin * OPAD;
  if (idx >= total) return;
  int o = idx % OPAD;
  int c = (idx / OPAD) % Cin;
  int tap = idx / (OPAD * Cin);
  float v = 0.f;
  if (o < Cout) v = w[(o * Cin + c) * 9 + tap] * g[o] * BN_INV;
  out[idx] = v;
}

// ---------------- wo1 weight repack: OIHW -> bf16 [tap][o][c], bn folded ----
__global__ __launch_bounds__(256) void k_repack_wo1bf(
    const float* __restrict__ w, const float* __restrict__ g,
    unsigned short* __restrict__ out) {
  int idx = blockIdx.x * 256 + threadIdx.x;  // 9*128*256 = 294912
  int c = idx & 255;
  int o = (idx >> 8) & 127;
  int tap = idx >> 15;
  float v = w[(o * 256 + c) * 9 + tap] * g[o] * BN_INV;
  out[idx] = f2bf(v);
}

// ---------------- t1 = relu(bn(conv1x1(xh, w1)))  (64ch out, 64x64) ---------
__global__ __launch_bounds__(256) void k_t1(
    const float* __restrict__ xh, const float* __restrict__ w1,
    const float* __restrict__ g, const float* __restrict__ bb,
    float* __restrict__ t1) {
  int t = threadIdx.x;
  int o = t & 63, ps = t >> 6;
  int p0 = blockIdx.x * 16 + ps * 4;  // over B*4096
  const float* ip = xh + (size_t)p0 * 128;
  const float* wp = w1 + o * 128;
  float a0 = 0, a1 = 0, a2 = 0, a3 = 0;
  for (int c = 0; c < 128; ++c) {
    float w = wp[c];
    a0 += w * ip[c];       a1 += w * ip[128 + c];
    a2 += w * ip[256 + c]; a3 += w * ip[384 + c];
  }
  float sc = g[o] * BN_INV, be = bb[o];
  t1[(size_t)(p0 + 0) * 64 + o] = fmaxf(a0 * sc + be, 0.f);
  t1[(size_t)(p0 + 1) * 64 + o] = fmaxf(a1 * sc + be, 0.f);
  t1[(size_t)(p0 + 2) * 64 + o] = fmaxf(a2 * sc + be, 0.f);
  t1[(size_t)(p0 + 3) * 64 + o] = fmaxf(a3 * sc + be, 0.f);
}

// ---------------- bilinear upsample 64->128 (align corners), NHWC -----------
template <int CH>
__global__ __launch_bounds__(256) void k_up(const float* __restrict__ in,
                                            float* __restrict__ out) {
  int t = threadIdx.x;
  int c = t % CH;
  int sub = t / CH;
  constexpr int PPB = 256 / CH;
  int g = blockIdx.x * PPB + sub;  // over B*16384
  int b = g >> 14;
  int pp = g & 16383;
  int oy = pp >> 7, ox = pp & 127;
  const float S = 63.0f / 127.0f;
  float fy = oy * S, fx = ox * S;
  int y0 = (int)fy, x0 = (int)fx;
  int y1 = min(y0 + 1, 63), x1 = min(x0 + 1, 63);
  float wy = fy - y0, wx = fx - x0;
  const float* base = in + (size_t)b * 4096 * CH;
  float v00 = base[(y0 * 64 + x0) * CH + c];
  float v01 = base[(y0 * 64 + x1) * CH + c];
  float v10 = base[(y1 * 64 + x0) * CH + c];
  float v11 = base[(y1 * 64 + x1) * CH + c];
  float top = v00 * (1.f - wx) + v01 * wx;
  float bot = v10 * (1.f - wx) + v11 * wx;
  out[(size_t)g * 128 + c] = top * (1.f - wy) + bot * wy;
}

// ---------------- SE: channel mean of xl ------------------------------------
__global__ __launch_bounds__(256) void k_semean(const float* __restrict__ xl,
                                                float* __restrict__ gmean) {
  int bid = blockIdx.x;  // B*64
  int b = bid >> 6, chunk = bid & 63;
  int t = threadIdx.x;
  int c = t & 127, sub = t >> 7;
  float s = 0.f;
  const float* base = xl + ((size_t)b * 16384 + chunk * 256) * 128;
  for (int p = sub; p < 256; p += 2) s += base[(size_t)p * 128 + c];
  __shared__ float lds[256];
  lds[t] = s;
  __syncthreads();
  if (t < 128) atomicAdd(&gmean[b * 128 + t], lds[t] + lds[t + 128]);
}

// ---------------- SE MLP + sigmoid + build per-batch effective w2 -----------
__global__ __launch_bounds__(128) void k_semlp(
    const float* __restrict__ gmean, const float* __restrict__ wf1,
    const float* __restrict__ bf1, const float* __restrict__ wf2,
    const float* __restrict__ bf2, const float* __restrict__ w2,
    float* __restrict__ weff) {
  int b = blockIdx.x;
  int t = threadIdx.x;  // 128
  __shared__ float m[128], hid[32], sg[128];
  m[t] = gmean[b * 128 + t] * (1.0f / 16384.0f);
  __syncthreads();
  if (t < 32) {
    float a = 0.f;
    for (int c = 0; c < 128; ++c) a += wf1[t * 128 + c] * m[c];
    hid[t] = fmaxf(a + bf1[t], 0.f);
  }
  __syncthreads();
  {
    float a = 0.f;
    for (int r = 0; r < 32; ++r) a += wf2[t * 32 + r] * hid[r];
    a += bf2[t];
    sg[t] = 1.f / (1.f + expf(-a));
  }
  __syncthreads();
  for (int o = 0; o < 64; ++o) {
    weff[((size_t)b * 64 + o) * 128 + t] =
        w2[o * 256 + t] * sg[t] + w2[o * 256 + 128 + t];
  }
}

// ---------------- x2 = relu(bn(weff_b . xl)) -> xcat ch 64..127 --------------
__global__ __launch_bounds__(256) void k_x2(
    const float* __restrict__ xl, const float* __restrict__ weff,
    const float* __restrict__ g, const float* __restrict__ bb,
    float* __restrict__ xcat) {
  int t = threadIdx.x;
  int o = t & 63, ps = t >> 6;
  int p0 = blockIdx.x * 16 + ps * 4;  // over B*16384
  int b = p0 >> 14;
  const float* ip = xl + (size_t)p0 * 128;
  const float* wp = weff + ((size_t)b * 64 + o) * 128;
  float a0 = 0, a1 = 0, a2 = 0, a3 = 0;
  for (int c = 0; c < 128; ++c) {
    float w = wp[c];
    a0 += w * ip[c];       a1 += w * ip[128 + c];
    a2 += w * ip[256 + c]; a3 += w * ip[384 + c];
  }
  float sc = g[o] * BN_INV, be = bb[o];
  xcat[(size_t)(p0 + 0) * 128 + 64 + o] = fmaxf(a0 * sc + be, 0.f);
  xcat[(size_t)(p0 + 1) * 128 + 64 + o] = fmaxf(a1 * sc + be, 0.f);
  xcat[(size_t)(p0 + 2) * 128 + 64 + o] = fmaxf(a2 * sc + be, 0.f);
  xcat[(size_t)(p0 + 3) * 128 + 64 + o] = fmaxf(a3 * sc + be, 0.f);
}

// ---------------- we conv 3x3, Cin=128 -> 25 (pad32), 128x128, bn (no relu) -
__global__ __launch_bounds__(256) void k_weconv(
    const float* __restrict__ xcat, const float* __restrict__ wer,
    const float* __restrict__ web, float* __restrict__ wk) {
  int t = threadIdx.x;
  int o = t & 31, psub = t >> 5;  // 8 groups x 4 pixels = 32 px/block
  int pixbase = blockIdx.x * 32;
  int b = pixbase >> 14;
  int pp = pixbase & 16383;
  int y = pp >> 7;
  int xb = (pp & 127) + psub * 4;
  float acc[4] = {0.f, 0.f, 0.f, 0.f};
  bool interior = (xb >= 1) && (xb + 4 <= 127);
  for (int ky = 0; ky < 3; ++ky) {
    int row = y + ky - 1;
    if ((unsigned)row >= 128u) continue;
    const float* rbase = xcat + (((size_t)b << 14) + (row << 7)) * 128;
    const float* wp = wer + (ky * 3 * 128) * 32 + o;
    if (interior) {
      const float* q = rbase + (size_t)(xb - 1) * 128;
      for (int c = 0; c < 128; ++c) {
        float v0 = q[c], v1 = q[128 + c], v2 = q[256 + c];
        float v3 = q[384 + c], v4 = q[512 + c], v5 = q[640 + c];
        float w0 = wp[c * 32], w1 = wp[(128 + c) * 32], w2 = wp[(256 + c) * 32];
        acc[0] += w0 * v0 + w1 * v1 + w2 * v2;
        acc[1] += w0 * v1 + w1 * v2 + w2 * v3;
        acc[2] += w0 * v2 + w1 * v3 + w2 * v4;
        acc[3] += w0 * v3 + w1 * v4 + w2 * v5;
      }
    } else {
      for (int c = 0; c < 128; ++c) {
        float v[6];
#pragma unroll
        for (int k = 0; k < 6; ++k) {
          int col = xb - 1 + k;
          int cc = min(max(col, 0), 127);
          float vv = rbase[(size_t)cc * 128 + c];
          v[k] = ((unsigned)col < 128u) ? vv : 0.f;
        }
        float w0 = wp[c * 32], w1 = wp[(128 + c) * 32], w2 = wp[(256 + c) * 32];
        acc[0] += w0 * v[0] + w1 * v[1] + w2 * v[2];
        acc[1] += w0 * v[1] + w1 * v[2] + w2 * v[3];
        acc[2] += w0 * v[2] + w1 * v[3] + w2 * v[4];
        acc[3] += w0 * v[3] + w1 * v[4] + w2 * v[5];
      }
    }
  }
  if (o < 25) {
#pragma unroll
    for (int i = 0; i < 4; ++i)
      wk[(size_t)(pixbase + psub * 4 + i) * 25 + o] = acc[i] + web[o];
  }
}

// ---------------- softmax over 25 channels ----------------------------------
__global__ __launch_bounds__(256) void k_softmax25(float* __restrict__ wk) {
  int g = blockIdx.x * 256 + threadIdx.x;  // B*16384
  float* p = wk + (size_t)g * 25;
  float mx = p[0];
#pragma unroll
  for (int i = 1; i < 25; ++i) mx = fmaxf(mx, p[i]);
  float e[25];
  float s = 0.f;
#pragma unroll
  for (int i = 0; i < 25; ++i) {
    e[i] = expf(p[i] - mx);
    s += e[i];
  }
  float inv = 1.f / s;
#pragma unroll
  for (int i = 0; i < 25; ++i) p[i] = e[i] * inv;
}

// ---------------- wr conv 3x3, 128->128, 64x64, bn+relu ---------------------
__global__ __launch_bounds__(256) void k_wrconv(
    const float* __restrict__ xh, const float* __restrict__ wrr,
    const float* __restrict__ bb, float* __restrict__ xr) {
  int t = threadIdx.x;
  int o = t & 127;
  int psub = t >> 7;  // 2 groups x 4 pixels = 8 px/block
  int pixbase = blockIdx.x * 8;  // over B*4096
  int b = pixbase >> 12;
  int pp = pixbase & 4095;
  int y = pp >> 6;
  int xb = (pp & 63) + psub * 4;
  float acc[4] = {0.f, 0.f, 0.f, 0.f};
  bool interior = (xb >= 1) && (xb + 4 <= 63);
  for (int ky = 0; ky < 3; ++ky) {
    int row = y + ky - 1;
    if ((unsigned)row >= 64u) continue;
    const float* rbase = xh + (((size_t)b << 12) + (row << 6)) * 128;
    const float* wp = wrr + (ky * 3 * 128) * 128 + o;
    if (interior) {
      const float* q = rbase + (size_t)(xb - 1) * 128;
      for (int c = 0; c < 128; ++c) {
        float v0 = q[c], v1 = q[128 + c], v2 = q[256 + c];
        float v3 = q[384 + c], v4 = q[512 + c], v5 = q[640 + c];
        float w0 = wp[c * 128], w1 = wp[(128 + c) * 128], w2 = wp[(256 + c) * 128];
        acc[0] += w0 * v0 + w1 * v1 + w2 * v2;
        acc[1] += w0 * v1 + w1 * v2 + w2 * v3;
        acc[2] += w0 * v2 + w1 * v3 + w2 * v4;
        acc[3] += w0 * v3 + w1 * v4 + w2 * v5;
      }
    } else {
      for (int c = 0; c < 128; ++c) {
        float v[6];
#pragma unroll
        for (int k = 0; k < 6; ++k) {
          int col = xb - 1 + k;
          int cc = min(max(col, 0), 63);
          float vv = rbase[(size_t)cc * 128 + c];
          v[k] = ((unsigned)col < 64u) ? vv : 0.f;
        }
        float w0 = wp[c * 128], w1 = wp[(128 + c) * 128], w2 = wp[(256 + c) * 128];
        acc[0] += w0 * v[0] + w1 * v[1] + w2 * v[2];
        acc[1] += w0 * v[1] + w1 * v[2] + w2 * v[3];
        acc[2] += w0 * v[2] + w1 * v[3] + w2 * v[4];
        acc[3] += w0 * v[3] + w1 * v[4] + w2 * v[5];
      }
    }
  }
  float be = bb[o];
  int gp0 = pixbase + psub * 4;
#pragma unroll
  for (int i = 0; i < 4; ++i)
    xr[(size_t)(gp0 + i) * 128 + o] = fmaxf(acc[i] + be, 0.f);
}

// ---------------- CARAFE reassembly -> padded bf16 buffer ch 0..127 ---------
__global__ __launch_bounds__(256) void k_carafe(const float* __restrict__ xup,
                                                const float* __restrict__ wk,
                                                unsigned short* __restrict__ pad) {
  int t = threadIdx.x;
  int c = t & 127;
  int sub = t >> 7;
  int g = blockIdx.x * 2 + sub;  // over B*16384
  int b = g >> 14, pp = g & 16383;
  int y = pp >> 7, x = pp & 127;
  __shared__ float wl[2][25];
  if ((t & 127) < 25) wl[sub][t & 127] = wk[(size_t)g * 25 + (t & 127)];
  __syncthreads();
  float acc = 0.f;
  const float* base = xup + ((size_t)b << 14) * 128;
#pragma unroll
  for (int i = 0; i < 5; ++i) {
    int row = y + 2 * i - 4;
    if ((unsigned)row >= 128u) continue;
#pragma unroll
    for (int jj = 0; jj < 5; ++jj) {
      int col = x + 2 * jj - 4;
      if ((unsigned)col >= 128u) continue;
      acc += wl[sub][i * 5 + jj] * base[((size_t)(row << 7) + col) * 128 + c];
    }
  }
  pad[((size_t)(b * 130 + y + 1) * 130 + (x + 1)) * 256 + c] = f2bf(acc);
}

// ---------------- xl fp32 NHWC -> padded bf16 buffer ch 128..255 ------------
__global__ __launch_bounds__(256) void k_xl2pad(const float* __restrict__ xl,
                                                unsigned short* __restrict__ pad) {
  int idx = blockIdx.x * 256 + threadIdx.x;  // 65536 px * 16 groups
  int c0 = (idx & 15) * 8;
  int p = idx >> 4;
  int b = p >> 14, pp = p & 16383;
  int y = pp >> 7, x = pp & 127;
  const float* s = xl + (size_t)p * 128 + c0;
  ushort8 o;
#pragma unroll
  for (int j = 0; j < 8; ++j) o[j] = f2bf(s[j]);
  *(ushort8*)(pad + ((size_t)(b * 130 + y + 1) * 130 + (x + 1)) * 256 + 128 + c0) = o;
}

// ---------------- wo1 conv as implicit-GEMM MFMA (bf16 in, fp32 acc) --------
// pad: [B][130][130][256] bf16 (X | xl, zero border). wb: [9][128][256] bf16.
// Each block: 64 pixels (half image row) x 128 couts. 4 waves, M16xN128 each.
__global__ __launch_bounds__(256) void k_wo1_mfma(
    const unsigned short* __restrict__ pad, const unsigned short* __restrict__ wb,
    const float* __restrict__ bb, float* __restrict__ y1) {
  int t = threadIdx.x;
  int wv = t >> 6;
  int l = t & 63;
  int blk = blockIdx.x;       // 1024
  int b = blk >> 8;
  int rr = blk & 255;
  int y = rr >> 1;
  int xseg = (rr & 1) << 6;   // 0 or 64
  int m0 = xseg + wv * 16;
  int xc = m0 + (l & 15);     // this lane's pixel col (A row)
  int kg = l >> 4;            // k-group 0..3

  // A: padded pixel (y+ky, xc+kx), channels kg*8 + [0,8) + 32*cc
  const unsigned short* abase =
      pad + ((size_t)(b * 130 + y) * 130 + xc) * 256 + kg * 8;
  // B: cout n = nf*16 + (l&15), same channel grouping
  const unsigned short* bbase = wb + (size_t)(l & 15) * 256 + kg * 8;

  f32x4 acc[8];
#pragma unroll
  for (int i = 0; i < 8; ++i) acc[i] = (f32x4){0.f, 0.f, 0.f, 0.f};

  for (int ky = 0; ky < 3; ++ky) {
    const unsigned short* arow = abase + (size_t)ky * 130 * 256;
    const unsigned short* brow = bbase + (size_t)ky * 3 * 128 * 256;
#pragma unroll
    for (int kx = 0; kx < 3; ++kx) {
      const unsigned short* ap = arow + kx * 256;
      const unsigned short* bp = brow + (size_t)kx * 128 * 256;
#pragma unroll
      for (int cc = 0; cc < 8; ++cc) {
        bf16x8 a = *(const bf16x8*)(ap + cc * 32);
#pragma unroll
        for (int nf = 0; nf < 8; ++nf) {
          bf16x8 bf = *(const bf16x8*)(bp + (size_t)nf * 16 * 256 + cc * 32);
          acc[nf] = __builtin_amdgcn_mfma_f32_16x16x32_bf16(a, bf, acc[nf], 0, 0, 0);
        }
      }
    }
  }

  // C/D layout: col = lane&15 (cout within frag), row = (lane>>4)*4 + r (pixel)
  int prow = m0 + (l >> 4) * 4;
  int ncol = l & 15;
  size_t pixbase = ((size_t)b << 14) + ((size_t)y << 7);
#pragma unroll
  for (int nf = 0; nf < 8; ++nf) {
    int o = nf * 16 + ncol;
    float be = bb[o];
#pragma unroll
    for (int r = 0; r < 4; ++r) {
      y1[(pixbase + prow + r) * 128 + o] = fmaxf(acc[nf][r] + be, 0.f);
    }
  }
}

// ---------------- wo2 1x1 conv + bn + relu, write NCHW fp32 ------------------
__global__ __launch_bounds__(256) void k_wo2(
    const float* __restrict__ y1, const float* __restrict__ w,
    const float* __restrict__ g, const float* __restrict__ bb,
    float* __restrict__ out) {
  int bid = blockIdx.x;  // B*128*2
  int xh_ = bid & 1;
  int y = (bid >> 1) & 127;
  int b = bid >> 8;
  int t = threadIdx.x;
  __shared__ float lds[128 * 65];
  const float* src = y1 + (((size_t)b << 14) + (y << 7) + (xh_ << 6)) * 128;
  for (int it = 0; it < 32; ++it) {
    int idx = it * 256 + t;
    int c = idx & 127, x = idx >> 7;
    lds[c * 65 + x] = src[(size_t)x * 128 + c];
  }
  __syncthreads();
  int x = t & 63, oq = t >> 6;
  size_t obase = (((size_t)b * 128) * 128 + y) * 128 + (xh_ << 6) + x;
  for (int o = oq * 32; o < oq * 32 + 32; ++o) {
    const float* wp = w + o * 128;
    float a0 = 0, a1 = 0;
    for (int c = 0; c < 128; c += 2) {
      a0 += lds[c * 65 + x] * wp[c];
      a1 += lds[(c + 1) * 65 + x] * wp[c + 1];
    }
    float r = fmaxf((a0 + a1) * (g[o] * BN_INV) + bb[o], 0.f);
    out[obase + (size_t)o * 16384] = r;
  }
}

extern "C" void kernel_launch(void* const* d_in, const int* in_sizes, int n_in,
                              void* d_out, int out_size, void* d_ws,
                              size_t ws_size, hipStream_t stream) {
  const float* x_h  = (const float*)d_in[0];
  const float* x_l  = (const float*)d_in[1];
  const float* wr   = (const float*)d_in[2];
  const float* wr_g = (const float*)d_in[3];
  const float* wr_b = (const float*)d_in[4];
  const float* w1   = (const float*)d_in[5];
  const float* w1_g = (const float*)d_in[6];
  const float* w1_b = (const float*)d_in[7];
  const float* w2   = (const float*)d_in[8];
  const float* w2_g = (const float*)d_in[9];
  const float* w2_b = (const float*)d_in[10];
  const float* we   = (const float*)d_in[11];
  const float* we_g = (const float*)d_in[12];
  const float* we_b = (const float*)d_in[13];
  const float* wf1  = (const float*)d_in[14];
  const float* bf1  = (const float*)d_in[15];
  const float* wf2  = (const float*)d_in[16];
  const float* bf2  = (const float*)d_in[17];
  const float* wo1  = (const float*)d_in[18];
  const float* wo1_g= (const float*)d_in[19];
  const float* wo1_b= (const float*)d_in[20];
  const float* wo2  = (const float*)d_in[21];
  const float* wo2_g= (const float*)d_in[22];
  const float* wo2_b= (const float*)d_in[23];
  float* out = (float*)d_out;

  float* ws = (float*)d_ws;
  // region0: xcat (8,388,608 f32) then reused as padded bf16 (8,652,800 u32)
  float* xcat  = ws;
  unsigned short* pad = (unsigned short*)ws;        // 4*130*130*256 bf16
  float* wkb   = ws + 8652800;       // 1,638,400
  float* xr    = wkb + 1638400;      // 2,097,152 (t1 aliases first 1,048,576)
  float* t1    = xr;
  float* xup   = xr + 2097152;       // 8,388,608 (y1 aliases after carafe)
  float* y1    = xup;
  float* gmean = xup + 8388608;      // 512
  float* weff  = gmean + 512;        // 32,768
  float* wr_r  = weff + 32768;       // 147,456
  float* we_r  = wr_r + 147456;      // 36,864
  unsigned short* wo1bf = (unsigned short*)(we_r + 36864);  // 294,912 bf16

  hipMemsetAsync(gmean, 0, 512 * sizeof(float), stream);

  k_repack<<<576, 256, 0, stream>>>(wr, wr_g, wr_r, 128, 128, 128);
  k_repack<<<144, 256, 0, stream>>>(we, we_g, we_r, 25, 128, 32);
  k_repack_wo1bf<<<1152, 256, 0, stream>>>(wo1, wo1_g, wo1bf);

  k_t1<<<1024, 256, 0, stream>>>(x_h, w1, w1_g, w1_b, t1);
  k_up<64><<<16384, 256, 0, stream>>>(t1, xcat);          // x1 -> ch 0..63
  k_semean<<<256, 256, 0, stream>>>(x_l, gmean);
  k_semlp<<<4, 128, 0, stream>>>(gmean, wf1, bf1, wf2, bf2, w2, weff);
  k_x2<<<4096, 256, 0, stream>>>(x_l, weff, w2_g, w2_b, xcat);  // ch 64..127
  k_weconv<<<2048, 256, 0, stream>>>(xcat, we_r, we_b, wkb);
  k_softmax25<<<256, 256, 0, stream>>>(wkb);

  // xcat dead -> region0 becomes padded bf16 conv input
  hipMemsetAsync(pad, 0, (size_t)4 * 130 * 130 * 256 * 2, stream);
  k_xl2pad<<<4096, 256, 0, stream>>>(x_l, pad);

  k_wrconv<<<2048, 256, 0, stream>>>(x_h, wr_r, wr_b, xr);
  k_up<128><<<32768, 256, 0, stream>>>(xr, xup);
  k_carafe<<<32768, 256, 0, stream>>>(xup, wkb, pad);     // X -> pad ch 0..127
  k_wo1_mfma<<<1024, 256, 0, stream>>>(pad, wo1bf, wo1_b, y1);
  k_wo2<<<1024, 256, 0, stream>>>(y1, wo2, wo2_g, wo2_b, out);
}

// Round 4
// 709.287 us; speedup vs baseline: 4.5088x; 1.9443x over previous
//
#include <hip/hip_runtime.h>
#include <hip/hip_bf16.h>

#define BN_INV 0.99999500003749968f  // 1/sqrt(1+1e-5)

typedef __attribute__((ext_vector_type(8))) short bf16x8;
typedef __attribute__((ext_vector_type(4))) float f32x4;
typedef __attribute__((ext_vector_type(8))) unsigned short ushort8;

__device__ inline unsigned short f2bf(float f) {
  union { float f; unsigned int u; } v;
  v.f = f;
  unsigned int r = v.u + 0x7FFFu + ((v.u >> 16) & 1u);
  return (unsigned short)(r >> 16);
}
__device__ inline float bf2f(unsigned short u) {
  union { unsigned int u; float f; } v;
  v.u = ((unsigned int)u) << 16;
  return v.f;
}

// ------ generic weight repack: OIHW -> bf16 [tap][o(OPAD)][c], bn folded ----
__global__ __launch_bounds__(256) void k_repack_bf(
    const float* __restrict__ w, const float* __restrict__ g,
    unsigned short* __restrict__ out, int Cout, int Cin, int OPAD, int TAPS) {
  int idx = blockIdx.x * 256 + threadIdx.x;
  int total = TAPS * Cin * OPAD;
  if (idx >= total) return;
  int c = idx % Cin;
  int o = (idx / Cin) % OPAD;
  int tap = idx / (Cin * OPAD);
  float v = 0.f;
  if (o < Cout) v = w[(o * Cin + c) * TAPS + tap] * g[o] * BN_INV;
  out[idx] = f2bf(v);
}

// ---------------- t1 = relu(bn(conv1x1(xh, w1)))  (64ch out, 64x64) ---------
__global__ __launch_bounds__(256) void k_t1(
    const float* __restrict__ xh, const float* __restrict__ w1,
    const float* __restrict__ g, const float* __restrict__ bb,
    float* __restrict__ t1) {
  int t = threadIdx.x;
  int o = t & 63, ps = t >> 6;
  int p0 = blockIdx.x * 16 + ps * 4;  // over B*4096
  const float* ip = xh + (size_t)p0 * 128;
  const float* wp = w1 + o * 128;
  float a0 = 0, a1 = 0, a2 = 0, a3 = 0;
  for (int c = 0; c < 128; ++c) {
    float w = wp[c];
    a0 += w * ip[c];       a1 += w * ip[128 + c];
    a2 += w * ip[256 + c]; a3 += w * ip[384 + c];
  }
  float sc = g[o] * BN_INV, be = bb[o];
  t1[(size_t)(p0 + 0) * 64 + o] = fmaxf(a0 * sc + be, 0.f);
  t1[(size_t)(p0 + 1) * 64 + o] = fmaxf(a1 * sc + be, 0.f);
  t1[(size_t)(p0 + 2) * 64 + o] = fmaxf(a2 * sc + be, 0.f);
  t1[(size_t)(p0 + 3) * 64 + o] = fmaxf(a3 * sc + be, 0.f);
}

// ------ bilinear up 64->128 of t1 (64ch) -> xcat_pad bf16 ch 0..63 ----------
__global__ __launch_bounds__(256) void k_up64_pad(const float* __restrict__ in,
                                                  unsigned short* __restrict__ pad) {
  int t = threadIdx.x;
  int cp = (t & 31) * 2;
  int sub = t >> 5;                  // 8 px/block
  int g = blockIdx.x * 8 + sub;      // B*16384
  int b = g >> 14, pp = g & 16383;
  int oy = pp >> 7, ox = pp & 127;
  const float S = 63.0f / 127.0f;
  float fy = oy * S, fx = ox * S;
  int y0 = (int)fy, x0 = (int)fx;
  int y1 = min(y0 + 1, 63), x1 = min(x0 + 1, 63);
  float wy = fy - y0, wx = fx - x0;
  const float* base = in + (size_t)b * 4096 * 64;
  float2 v00 = *(const float2*)(base + ((y0 << 6) + x0) * 64 + cp);
  float2 v01 = *(const float2*)(base + ((y0 << 6) + x1) * 64 + cp);
  float2 v10 = *(const float2*)(base + ((y1 << 6) + x0) * 64 + cp);
  float2 v11 = *(const float2*)(base + ((y1 << 6) + x1) * 64 + cp);
  float r0 = (v00.x * (1.f - wx) + v01.x * wx) * (1.f - wy) +
             (v10.x * (1.f - wx) + v11.x * wx) * wy;
  float r1 = (v00.y * (1.f - wx) + v01.y * wx) * (1.f - wy) +
             (v10.y * (1.f - wx) + v11.y * wx) * wy;
  ushort2 o2; o2.x = f2bf(r0); o2.y = f2bf(r1);
  *(ushort2*)(pad + ((size_t)(b * 130 + oy + 1) * 130 + ox + 1) * 128 + cp) = o2;
}

// ---------------- SE: channel mean of xl ------------------------------------
__global__ __launch_bounds__(256) void k_semean(const float* __restrict__ xl,
                                                float* __restrict__ gmean) {
  int bid = blockIdx.x;  // B*64
  int b = bid >> 6, chunk = bid & 63;
  int t = threadIdx.x;
  int c = t & 127, sub = t >> 7;
  float s = 0.f;
  const float* base = xl + ((size_t)b * 16384 + chunk * 256) * 128;
  for (int p = sub; p < 256; p += 2) s += base[(size_t)p * 128 + c];
  __shared__ float lds[256];
  lds[t] = s;
  __syncthreads();
  if (t < 128) atomicAdd(&gmean[b * 128 + t], lds[t] + lds[t + 128]);
}

// ---------------- SE MLP + sigmoid + build per-batch effective w2 -----------
__global__ __launch_bounds__(128) void k_semlp(
    const float* __restrict__ gmean, const float* __restrict__ wf1,
    const float* __restrict__ bf1, const float* __restrict__ wf2,
    const float* __restrict__ bf2, const float* __restrict__ w2,
    float* __restrict__ weff) {
  int b = blockIdx.x;
  int t = threadIdx.x;  // 128
  __shared__ float m[128], hid[32], sg[128];
  m[t] = gmean[b * 128 + t] * (1.0f / 16384.0f);
  __syncthreads();
  if (t < 32) {
    float a = 0.f;
    for (int c = 0; c < 128; ++c) a += wf1[t * 128 + c] * m[c];
    hid[t] = fmaxf(a + bf1[t], 0.f);
  }
  __syncthreads();
  {
    float a = 0.f;
    for (int r = 0; r < 32; ++r) a += wf2[t * 32 + r] * hid[r];
    a += bf2[t];
    sg[t] = 1.f / (1.f + expf(-a));
  }
  __syncthreads();
  for (int o = 0; o < 64; ++o) {
    weff[((size_t)b * 64 + o) * 128 + t] =
        w2[o * 256 + t] * sg[t] + w2[o * 256 + 128 + t];
  }
}

// ------ x2 = relu(bn(weff_b . xl)) -> xcat_pad bf16 ch 64..127 ---------------
__global__ __launch_bounds__(256) void k_x2_pad(
    const float* __restrict__ xl, const float* __restrict__ weff,
    const float* __restrict__ g, const float* __restrict__ bb,
    unsigned short* __restrict__ pad) {
  int t = threadIdx.x;
  int o = t & 63, ps = t >> 6;
  int p0 = blockIdx.x * 16 + ps * 4;  // over B*16384
  int b = p0 >> 14;
  int pp = p0 & 16383;
  int y = pp >> 7, x0 = pp & 127;
  const float* ip = xl + (size_t)p0 * 128;
  const float* wp = weff + ((size_t)b * 64 + o) * 128;
  float a0 = 0, a1 = 0, a2 = 0, a3 = 0;
  for (int c = 0; c < 128; ++c) {
    float w = wp[c];
    a0 += w * ip[c];       a1 += w * ip[128 + c];
    a2 += w * ip[256 + c]; a3 += w * ip[384 + c];
  }
  float sc = g[o] * BN_INV, be = bb[o];
  size_t rb = (size_t)(b * 130 + y + 1) * 130;
  pad[(rb + x0 + 1) * 128 + 64 + o] = f2bf(fmaxf(a0 * sc + be, 0.f));
  pad[(rb + x0 + 2) * 128 + 64 + o] = f2bf(fmaxf(a1 * sc + be, 0.f));
  pad[(rb + x0 + 3) * 128 + 64 + o] = f2bf(fmaxf(a2 * sc + be, 0.f));
  pad[(rb + x0 + 4) * 128 + 64 + o] = f2bf(fmaxf(a3 * sc + be, 0.f));
}

// ------ xh fp32 NHWC -> padded bf16 [B][66][66][128] ------------------------
__global__ __launch_bounds__(256) void k_xh2pad(const float* __restrict__ xh,
                                                unsigned short* __restrict__ xhp) {
  int idx = blockIdx.x * 256 + threadIdx.x;  // 4*4096*16
  int c0 = (idx & 15) * 8;
  int p = idx >> 4;
  int b = p >> 12, pp = p & 4095;
  int y = pp >> 6, x = pp & 63;
  const float* s = xh + (size_t)p * 128 + c0;
  ushort8 o;
#pragma unroll
  for (int j = 0; j < 8; ++j) o[j] = f2bf(s[j]);
  *(ushort8*)(xhp + ((size_t)(b * 66 + y + 1) * 66 + (x + 1)) * 128 + c0) = o;
}

// ------ xl fp32 NHWC -> padded bf16 wo1-input ch 128..255 --------------------
__global__ __launch_bounds__(256) void k_xl2pad(const float* __restrict__ xl,
                                                unsigned short* __restrict__ pad) {
  int idx = blockIdx.x * 256 + threadIdx.x;  // 65536 px * 16 groups
  int c0 = (idx & 15) * 8;
  int p = idx >> 4;
  int b = p >> 14, pp = p & 16383;
  int y = pp >> 7, x = pp & 127;
  const float* s = xl + (size_t)p * 128 + c0;
  ushort8 o;
#pragma unroll
  for (int j = 0; j < 8; ++j) o[j] = f2bf(s[j]);
  *(ushort8*)(pad + ((size_t)(b * 130 + y + 1) * 130 + (x + 1)) * 256 + 128 + c0) = o;
}

// ------ we conv MFMA: xcat_pad[130x130x128] x [9][32][128] -> wkb fp32 -------
__global__ __launch_bounds__(256) void k_we_mfma(
    const unsigned short* __restrict__ pad, const unsigned short* __restrict__ wb,
    const float* __restrict__ web, float* __restrict__ wk) {
  int t = threadIdx.x;
  int wv = t >> 6, l = t & 63;
  int blk = blockIdx.x;  // 1024
  int b = blk >> 8, rr = blk & 255;
  int y = rr >> 1;
  int xseg = (rr & 1) << 6;
  int m0 = xseg + wv * 16;
  int xc = m0 + (l & 15);
  int kg = l >> 4;
  const unsigned short* abase =
      pad + ((size_t)(b * 130 + y) * 130 + xc) * 128 + kg * 8;
  const unsigned short* bbase = wb + (size_t)(l & 15) * 128 + kg * 8;
  f32x4 acc[2];
#pragma unroll
  for (int i = 0; i < 2; ++i) acc[i] = (f32x4){0.f, 0.f, 0.f, 0.f};
  for (int ky = 0; ky < 3; ++ky) {
    const unsigned short* arow = abase + (size_t)ky * 130 * 128;
    const unsigned short* brow = bbase + (size_t)ky * 3 * 32 * 128;
#pragma unroll
    for (int kx = 0; kx < 3; ++kx) {
      const unsigned short* ap = arow + kx * 128;
      const unsigned short* bp = brow + kx * 32 * 128;
#pragma unroll
      for (int cc = 0; cc < 4; ++cc) {
        bf16x8 a = *(const bf16x8*)(ap + cc * 32);
#pragma unroll
        for (int nf = 0; nf < 2; ++nf) {
          bf16x8 bfr = *(const bf16x8*)(bp + nf * 16 * 128 + cc * 32);
          acc[nf] = __builtin_amdgcn_mfma_f32_16x16x32_bf16(a, bfr, acc[nf], 0, 0, 0);
        }
      }
    }
  }
  int prow = m0 + (l >> 4) * 4;
  int ncol = l & 15;
  size_t pixb = ((size_t)b << 14) + ((size_t)y << 7);
#pragma unroll
  for (int nf = 0; nf < 2; ++nf) {
    int n = nf * 16 + ncol;
    if (n < 25) {
      float be = web[n];
#pragma unroll
      for (int r = 0; r < 4; ++r)
        wk[(pixb + prow + r) * 25 + n] = acc[nf][r] + be;
    }
  }
}

// ---------------- softmax over 25 channels ----------------------------------
__global__ __launch_bounds__(256) void k_softmax25(float* __restrict__ wk) {
  int g = blockIdx.x * 256 + threadIdx.x;  // B*16384
  float* p = wk + (size_t)g * 25;
  float mx = p[0];
#pragma unroll
  for (int i = 1; i < 25; ++i) mx = fmaxf(mx, p[i]);
  float e[25];
  float s = 0.f;
#pragma unroll
  for (int i = 0; i < 25; ++i) {
    e[i] = expf(p[i] - mx);
    s += e[i];
  }
  float inv = 1.f / s;
#pragma unroll
  for (int i = 0; i < 25; ++i) p[i] = e[i] * inv;
}

// ------ wr conv MFMA: xh_pad[66x66x128] x [9][128][128] -> xr bf16, relu ----
__global__ __launch_bounds__(256) void k_wr_mfma(
    const unsigned short* __restrict__ xhp, const unsigned short* __restrict__ wb,
    const float* __restrict__ bb, unsigned short* __restrict__ xr) {
  int t = threadIdx.x;
  int wv = t >> 6, l = t & 63;
  int blk = blockIdx.x;  // 512
  int b = blk >> 7, rr = blk & 127;
  int y = rr >> 1;
  int xseg = (rr & 1) << 5;
  int pxg = wv & 1, h = wv >> 1;
  int m0 = xseg + pxg * 16;
  int xc = m0 + (l & 15);
  int kg = l >> 4;
  const unsigned short* abase =
      xhp + ((size_t)(b * 66 + y) * 66 + xc) * 128 + kg * 8;
  const unsigned short* bbase = wb + (size_t)(h * 64 + (l & 15)) * 128 + kg * 8;
  f32x4 acc[4];
#pragma unroll
  for (int i = 0; i < 4; ++i) acc[i] = (f32x4){0.f, 0.f, 0.f, 0.f};
  for (int ky = 0; ky < 3; ++ky) {
    const unsigned short* arow = abase + (size_t)ky * 66 * 128;
    const unsigned short* brow = bbase + (size_t)ky * 3 * 128 * 128;
#pragma unroll
    for (int kx = 0; kx < 3; ++kx) {
      const unsigned short* ap = arow + kx * 128;
      const unsigned short* bp = brow + kx * 128 * 128;
#pragma unroll
      for (int cc = 0; cc < 4; ++cc) {
        bf16x8 a = *(const bf16x8*)(ap + cc * 32);
#pragma unroll
        for (int nf = 0; nf < 4; ++nf) {
          bf16x8 bfr = *(const bf16x8*)(bp + nf * 16 * 128 + cc * 32);
          acc[nf] = __builtin_amdgcn_mfma_f32_16x16x32_bf16(a, bfr, acc[nf], 0, 0, 0);
        }
      }
    }
  }
  int prow = m0 + (l >> 4) * 4;
  int ncol = l & 15;
  size_t pixb = ((size_t)b << 12) + ((size_t)y << 6);
#pragma unroll
  for (int nf = 0; nf < 4; ++nf) {
    int o = h * 64 + nf * 16 + ncol;
    float be = bb[o];
#pragma unroll
    for (int r = 0; r < 4; ++r)
      xr[(pixb + prow + r) * 128 + o] = f2bf(fmaxf(acc[nf][r] + be, 0.f));
  }
}

// ------ bilinear up 64->128 of xr (bf16,128ch) -> xup bf16 -------------------
__global__ __launch_bounds__(256) void k_up128_bf(
    const unsigned short* __restrict__ in, unsigned short* __restrict__ outb) {
  int t = threadIdx.x;
  int cp = (t & 63) * 2;
  int sub = t >> 6;                  // 4 px/block
  int g = blockIdx.x * 4 + sub;      // B*16384
  int b = g >> 14, pp = g & 16383;
  int oy = pp >> 7, ox = pp & 127;
  const float S = 63.0f / 127.0f;
  float fy = oy * S, fx = ox * S;
  int y0 = (int)fy, x0 = (int)fx;
  int y1 = min(y0 + 1, 63), x1 = min(x0 + 1, 63);
  float wy = fy - y0, wx = fx - x0;
  const unsigned short* base = in + (size_t)b * 4096 * 128;
  const unsigned short* p00 = base + ((y0 << 6) + x0) * 128 + cp;
  const unsigned short* p01 = base + ((y0 << 6) + x1) * 128 + cp;
  const unsigned short* p10 = base + ((y1 << 6) + x0) * 128 + cp;
  const unsigned short* p11 = base + ((y1 << 6) + x1) * 128 + cp;
  ushort2 o2;
  unsigned short r[2];
#pragma unroll
  for (int j = 0; j < 2; ++j) {
    float top = bf2f(p00[j]) * (1.f - wx) + bf2f(p01[j]) * wx;
    float bot = bf2f(p10[j]) * (1.f - wx) + bf2f(p11[j]) * wx;
    r[j] = f2bf(top * (1.f - wy) + bot * wy);
  }
  o2.x = r[0]; o2.y = r[1];
  *(ushort2*)(outb + (size_t)g * 128 + cp) = o2;
}

// ------ CARAFE reassembly (bf16 in) -> wo1-input pad ch 0..127 ---------------
__global__ __launch_bounds__(256) void k_carafe_bf(
    const unsigned short* __restrict__ xup, const float* __restrict__ wk,
    unsigned short* __restrict__ pad) {
  int t = threadIdx.x;
  int cp = (t & 63) * 2;
  int sub = t >> 6;                  // 4 px/block
  int g = blockIdx.x * 4 + sub;
  int b = g >> 14, pp = g & 16383;
  int y = pp >> 7, x = pp & 127;
  __shared__ float wl[4][25];
  if (t < 100) wl[t / 25][t % 25] = wk[(size_t)(blockIdx.x * 4 + t / 25) * 25 + (t % 25)];
  __syncthreads();
  float a0 = 0.f, a1 = 0.f;
  const unsigned short* base = xup + ((size_t)b << 14) * 128 + cp;
#pragma unroll
  for (int i = 0; i < 5; ++i) {
    int row = y + 2 * i - 4;
    if ((unsigned)row >= 128u) continue;
#pragma unroll
    for (int jj = 0; jj < 5; ++jj) {
      int col = x + 2 * jj - 4;
      if ((unsigned)col >= 128u) continue;
      const unsigned short* q = base + (size_t)((row << 7) + col) * 128;
      float w = wl[sub][i * 5 + jj];
      a0 += w * bf2f(q[0]);
      a1 += w * bf2f(q[1]);
    }
  }
  ushort2 o2; o2.x = f2bf(a0); o2.y = f2bf(a1);
  *(ushort2*)(pad + ((size_t)(b * 130 + y + 1) * 130 + (x + 1)) * 256 + cp) = o2;
}

// ------ wo1 conv MFMA: pad[130x130x256] x [9][128][256] -> y1 bf16, relu ----
__global__ __launch_bounds__(256) void k_wo1_mfma(
    const unsigned short* __restrict__ pad, const unsigned short* __restrict__ wb,
    const float* __restrict__ bb, unsigned short* __restrict__ y1) {
  int t = threadIdx.x;
  int wv = t >> 6;
  int l = t & 63;
  int blk = blockIdx.x;  // 1024
  int b = blk >> 8;
  int rr = blk & 255;
  int y = rr >> 1;
  int xseg = (rr & 1) << 6;
  int m0 = xseg + wv * 16;
  int xc = m0 + (l & 15);
  int kg = l >> 4;
  const unsigned short* abase =
      pad + ((size_t)(b * 130 + y) * 130 + xc) * 256 + kg * 8;
  const unsigned short* bbase = wb + (size_t)(l & 15) * 256 + kg * 8;
  f32x4 acc[8];
#pragma unroll
  for (int i = 0; i < 8; ++i) acc[i] = (f32x4){0.f, 0.f, 0.f, 0.f};
  for (int ky = 0; ky < 3; ++ky) {
    const unsigned short* arow = abase + (size_t)ky * 130 * 256;
    const unsigned short* brow = bbase + (size_t)ky * 3 * 128 * 256;
#pragma unroll
    for (int kx = 0; kx < 3; ++kx) {
      const unsigned short* ap = arow + kx * 256;
      const unsigned short* bp = brow + (size_t)kx * 128 * 256;
#pragma unroll
      for (int cc = 0; cc < 8; ++cc) {
        bf16x8 a = *(const bf16x8*)(ap + cc * 32);
#pragma unroll
        for (int nf = 0; nf < 8; ++nf) {
          bf16x8 bfr = *(const bf16x8*)(bp + (size_t)nf * 16 * 256 + cc * 32);
          acc[nf] = __builtin_amdgcn_mfma_f32_16x16x32_bf16(a, bfr, acc[nf], 0, 0, 0);
        }
      }
    }
  }
  int prow = m0 + (l >> 4) * 4;
  int ncol = l & 15;
  size_t pixbase = ((size_t)b << 14) + ((size_t)y << 7);
#pragma unroll
  for (int nf = 0; nf < 8; ++nf) {
    int o = nf * 16 + ncol;
    float be = bb[o];
#pragma unroll
    for (int r = 0; r < 4; ++r)
      y1[(pixbase + prow + r) * 128 + o] = f2bf(fmaxf(acc[nf][r] + be, 0.f));
  }
}

// ------ wo2 1x1 MFMA: y1 bf16 x [128][128] -> out NCHW fp32, relu ------------
__global__ __launch_bounds__(256) void k_wo2_mfma(
    const unsigned short* __restrict__ y1, const unsigned short* __restrict__ wb,
    const float* __restrict__ bb, float* __restrict__ out) {
  int t = threadIdx.x;
  int wv = t >> 6, l = t & 63;
  int blk = blockIdx.x;  // 1024
  int b = blk >> 8, rr = blk & 255;
  int y = rr >> 1;
  int xseg = (rr & 1) << 6;
  int m0 = xseg + wv * 16;
  int xc = m0 + (l & 15);
  int kg = l >> 4;
  const unsigned short* abase =
      y1 + ((size_t)((b << 14) + (y << 7) + xc)) * 128 + kg * 8;
  const unsigned short* bbase = wb + (size_t)(l & 15) * 128 + kg * 8;
  f32x4 acc[8];
#pragma unroll
  for (int i = 0; i < 8; ++i) acc[i] = (f32x4){0.f, 0.f, 0.f, 0.f};
#pragma unroll
  for (int cc = 0; cc < 4; ++cc) {
    bf16x8 a = *(const bf16x8*)(abase + cc * 32);
#pragma unroll
    for (int nf = 0; nf < 8; ++nf) {
      bf16x8 bfr = *(const bf16x8*)(bbase + nf * 16 * 128 + cc * 32);
      acc[nf] = __builtin_amdgcn_mfma_f32_16x16x32_bf16(a, bfr, acc[nf], 0, 0, 0);
    }
  }
  int prow = m0 + (l >> 4) * 4;
  int ncol = l & 15;
#pragma unroll
  for (int nf = 0; nf < 8; ++nf) {
    int o = nf * 16 + ncol;
    float be = bb[o];
    f32x4 r;
#pragma unroll
    for (int k = 0; k < 4; ++k) r[k] = fmaxf(acc[nf][k] + be, 0.f);
    *(f32x4*)(out + (((size_t)(b * 128 + o) * 128 + y) << 7) + prow) = r;
  }
}

extern "C" void kernel_launch(void* const* d_in, const int* in_sizes, int n_in,
                              void* d_out, int out_size, void* d_ws,
                              size_t ws_size, hipStream_t stream) {
  const float* x_h  = (const float*)d_in[0];
  const float* x_l  = (const float*)d_in[1];
  const float* wr   = (const float*)d_in[2];
  const float* wr_g = (const float*)d_in[3];
  const float* wr_b = (const float*)d_in[4];
  const float* w1   = (const float*)d_in[5];
  const float* w1_g = (const float*)d_in[6];
  const float* w1_b = (const float*)d_in[7];
  const float* w2   = (const float*)d_in[8];
  const float* w2_g = (const float*)d_in[9];
  const float* w2_b = (const float*)d_in[10];
  const float* we   = (const float*)d_in[11];
  const float* we_g = (const float*)d_in[12];
  const float* we_b = (const float*)d_in[13];
  const float* wf1  = (const float*)d_in[14];
  const float* bf1  = (const float*)d_in[15];
  const float* wf2  = (const float*)d_in[16];
  const float* bf2  = (const float*)d_in[17];
  const float* wo1  = (const float*)d_in[18];
  const float* wo1_g= (const float*)d_in[19];
  const float* wo1_b= (const float*)d_in[20];
  const float* wo2  = (const float*)d_in[21];
  const float* wo2_g= (const float*)d_in[22];
  const float* wo2_b= (const float*)d_in[23];
  float* out = (float*)d_out;

  float* ws = (float*)d_ws;
  // layout (f32 offsets), total 20,141,568 f32 = 80.57 MB
  unsigned short* pad      = (unsigned short*)ws;                  // [4][130][130][256] bf16
  unsigned short* xcat_pad = (unsigned short*)(ws + 8652800);      // [4][130][130][128] bf16
  unsigned short* xup      = xcat_pad;                             // reuse after we_mfma
  float* wkb   = ws + 12979200;                                    // 1,638,400 f32
  float* t1    = ws + 14617600;                                    // 1,048,576 f32
  unsigned short* xr = (unsigned short*)t1;                        // reuse after up64
  float* y1reg = ws + 15666176;                                    // 4,194,304 f32 region
  unsigned short* y1     = (unsigned short*)y1reg;                 // 8,388,608 bf16 (late)
  unsigned short* xh_pad = (unsigned short*)y1reg;                 // 2,230,272 bf16 (early)
  float* gmean = ws + 19860480;                                    // 512
  float* weff  = gmean + 512;                                      // 32,768
  unsigned short* wr_bf = (unsigned short*)(weff + 32768);         // 147,456 bf16
  unsigned short* we_bf = (unsigned short*)(weff + 32768 + 73728); // 36,864 bf16
  unsigned short* wo1bf = (unsigned short*)(weff + 32768 + 73728 + 18432);  // 294,912 bf16
  unsigned short* wo2bf = (unsigned short*)(weff + 32768 + 73728 + 18432 + 147456); // 16,384 bf16

  hipMemsetAsync(gmean, 0, 512 * sizeof(float), stream);
  hipMemsetAsync(pad, 0, (size_t)4 * 130 * 130 * 256 * 2, stream);
  hipMemsetAsync(xcat_pad, 0, (size_t)4 * 130 * 130 * 128 * 2, stream);
  hipMemsetAsync(xh_pad, 0, (size_t)4 * 66 * 66 * 128 * 2, stream);

  k_repack_bf<<<576, 256, 0, stream>>>(wr, wr_g, wr_bf, 128, 128, 128, 9);
  k_repack_bf<<<144, 256, 0, stream>>>(we, we_g, we_bf, 25, 128, 32, 9);
  k_repack_bf<<<1152, 256, 0, stream>>>(wo1, wo1_g, wo1bf, 128, 256, 128, 9);
  k_repack_bf<<<64, 256, 0, stream>>>(wo2, wo2_g, wo2bf, 128, 128, 128, 1);

  k_t1<<<1024, 256, 0, stream>>>(x_h, w1, w1_g, w1_b, t1);
  k_up64_pad<<<8192, 256, 0, stream>>>(t1, xcat_pad);          // ch 0..63
  k_semean<<<256, 256, 0, stream>>>(x_l, gmean);
  k_semlp<<<4, 128, 0, stream>>>(gmean, wf1, bf1, wf2, bf2, w2, weff);
  k_x2_pad<<<4096, 256, 0, stream>>>(x_l, weff, w2_g, w2_b, xcat_pad);  // ch 64..127
  k_xh2pad<<<1024, 256, 0, stream>>>(x_h, xh_pad);
  k_xl2pad<<<4096, 256, 0, stream>>>(x_l, pad);

  k_we_mfma<<<1024, 256, 0, stream>>>(xcat_pad, we_bf, we_b, wkb);
  k_softmax25<<<256, 256, 0, stream>>>(wkb);
  k_wr_mfma<<<512, 256, 0, stream>>>(xh_pad, wr_bf, wr_b, xr);
  k_up128_bf<<<16384, 256, 0, stream>>>(xr, xup);              // xcat_pad now dead
  k_carafe_bf<<<16384, 256, 0, stream>>>(xup, wkb, pad);       // X -> pad ch 0..127
  k_wo1_mfma<<<1024, 256, 0, stream>>>(pad, wo1bf, wo1_b, y1); // xh_pad dead
  k_wo2_mfma<<<1024, 256, 0, stream>>>(y1, wo2bf, wo2_b, out);
}

// Round 5
// 410.863 us; speedup vs baseline: 7.7837x; 1.7263x over previous
//
#include <hip/hip_runtime.h>
#include <hip/hip_bf16.h>

#define BN_INV 0.99999500003749968f  // 1/sqrt(1+1e-5)

typedef __attribute__((ext_vector_type(8))) short bf16x8;
typedef __attribute__((ext_vector_type(4))) float f32x4;
typedef __attribute__((ext_vector_type(8))) unsigned short ushort8;
typedef unsigned short u16;

__device__ inline u16 f2bf(float f) {
  union { float f; unsigned int u; } v;
  v.f = f;
  unsigned int r = v.u + 0x7FFFu + ((v.u >> 16) & 1u);
  return (u16)(r >> 16);
}
__device__ inline float bf2f(u16 u) {
  union { unsigned int u; float f; } v;
  v.u = ((unsigned int)u) << 16;
  return v.f;
}

// async global->LDS, 16B per lane, dest = uniform base + lane*16
#define GLOAD_LDS16(g, l)                                              \
  __builtin_amdgcn_global_load_lds(                                    \
      (const __attribute__((address_space(1))) unsigned int*)(g),      \
      (__attribute__((address_space(3))) unsigned int*)(l), 16, 0, 0)

// ------ generic weight repack: OIHW -> bf16 [tap][o(OPAD)][c], bn folded ----
__global__ __launch_bounds__(256) void k_repack_bf(
    const float* __restrict__ w, const float* __restrict__ g,
    u16* __restrict__ out, int Cout, int Cin, int OPAD, int TAPS) {
  int idx = blockIdx.x * 256 + threadIdx.x;
  int total = TAPS * Cin * OPAD;
  if (idx >= total) return;
  int c = idx % Cin;
  int o = (idx / Cin) % OPAD;
  int tap = idx / (Cin * OPAD);
  float v = 0.f;
  if (o < Cout) v = w[(o * Cin + c) * TAPS + tap] * g[o] * BN_INV;
  out[idx] = f2bf(v);
}

// ================= tiled implicit-GEMM 3x3 conv, bf16 MFMA ==================
// pad: [B][PADW][PADW][CIN] bf16, zero ring. wb: [9][NOUT][CIN] bf16 (bn folded)
// block = 4 waves, tile = TILE_M px (one row chunk) x NB couts.
// K-steps: 9 taps x CIN/64. LDS A[TILE_M][64], B[NB][64], double-buffered.
// XOR swizzle: 16B slot ^= (row&7) (pre-swizzled global src, swizzled ds_read).
template <int PADW, int CIN, int NOUT, int NB, int TILE_M, int EPI>
__global__ __launch_bounds__(256, 2) void k_conv_mfma(
    const u16* __restrict__ pad, const u16* __restrict__ wb,
    const float* __restrict__ bias, void* __restrict__ outp) {
  constexpr int H = PADW - 2;          // output H == W
  constexpr int NSEG = NOUT / NB;
  constexpr int KQ = CIN / 64;
  constexpr int NSTEPS = 9 * KQ;
  constexpr int WM = TILE_M / 4;       // px per wave
  constexpr int MF = WM / 16;
  constexpr int NF = NB / 16;
  __shared__ alignas(16) u16 As[2][TILE_M * 64];
  __shared__ alignas(16) u16 Bs[2][NB * 64];

  int tid = threadIdx.x, wv = tid >> 6, l = tid & 63;
  int bid = blockIdx.x;
  int ns = (NSEG > 1) ? (bid % NSEG) : 0;
  int row = (NSEG > 1) ? (bid / NSEG) : bid;
  int b = row / H, y = row % H;
  const u16* pbat = pad + (size_t)b * PADW * PADW * CIN;

  auto stage = [&](int t, int bufi) {
    int tap = t / KQ;
    int ch0 = (t % KQ) * 64;
    int ky = tap / 3, kx = tap % 3;
    const u16* arow = pbat + ((size_t)(y + ky) * PADW + kx) * CIN + ch0;
#pragma unroll
    for (int j = 0; j < TILE_M * 8 / 256; ++j) {
      int q = j * 256 + tid;
      int px = q >> 3;
      int sl = (q & 7) ^ (px & 7);
      GLOAD_LDS16(arow + (size_t)px * CIN + sl * 8,
                  (char*)&As[bufi][0] + (size_t)(j * 256 + (tid & ~63)) * 16);
    }
    const u16* brow = wb + ((size_t)tap * NOUT + ns * NB) * CIN + ch0;
#pragma unroll
    for (int j = 0; j < NB * 8 / 256; ++j) {
      int q = j * 256 + tid;
      int co = q >> 3;
      int sl = (q & 7) ^ (co & 7);
      GLOAD_LDS16(brow + (size_t)co * CIN + sl * 8,
                  (char*)&Bs[bufi][0] + (size_t)(j * 256 + (tid & ~63)) * 16);
    }
  };

  f32x4 acc[MF][NF];
#pragma unroll
  for (int m = 0; m < MF; ++m)
#pragma unroll
    for (int n = 0; n < NF; ++n) acc[m][n] = (f32x4){0.f, 0.f, 0.f, 0.f};

  stage(0, 0);
  for (int t = 0; t < NSTEPS; ++t) {
    __syncthreads();
    if (t + 1 < NSTEPS) stage(t + 1, (t + 1) & 1);
    const u16* Ab = &As[t & 1][0];
    const u16* Bb = &Bs[t & 1][0];
    bf16x8 Bf[2][NF];
#pragma unroll
    for (int kf = 0; kf < 2; ++kf)
#pragma unroll
      for (int n = 0; n < NF; ++n) {
        int co = n * 16 + (l & 15);
        int sl = (kf * 4 + (l >> 4)) ^ (co & 7);
        Bf[kf][n] = *(const bf16x8*)((const char*)Bb + co * 128 + sl * 16);
      }
#pragma unroll
    for (int m = 0; m < MF; ++m) {
      int px = wv * WM + m * 16 + (l & 15);
      int s0 = (l >> 4) ^ (px & 7);
      int s1 = (4 + (l >> 4)) ^ (px & 7);
      bf16x8 a0 = *(const bf16x8*)((const char*)Ab + px * 128 + s0 * 16);
      bf16x8 a1 = *(const bf16x8*)((const char*)Ab + px * 128 + s1 * 16);
#pragma unroll
      for (int n = 0; n < NF; ++n) {
        acc[m][n] = __builtin_amdgcn_mfma_f32_16x16x32_bf16(a0, Bf[0][n], acc[m][n], 0, 0, 0);
        acc[m][n] = __builtin_amdgcn_mfma_f32_16x16x32_bf16(a1, Bf[1][n], acc[m][n], 0, 0, 0);
      }
    }
  }

  int ncol = l & 15, rq = l >> 4;
  size_t pixb = ((size_t)b * H + y) * H;
  if (EPI == 0) {  // bf16 NHWC (stride NOUT), bias + relu
    u16* ob = (u16*)outp;
#pragma unroll
    for (int m = 0; m < MF; ++m) {
      int px0 = wv * WM + m * 16 + rq * 4;
#pragma unroll
      for (int n = 0; n < NF; ++n) {
        int o = ns * NB + n * 16 + ncol;
        float be = bias[o];
#pragma unroll
        for (int r = 0; r < 4; ++r)
          ob[(pixb + px0 + r) * NOUT + o] = f2bf(fmaxf(acc[m][n][r] + be, 0.f));
      }
    }
  } else {  // EPI==1: fp32, 25-channel (we), bias only
    float* wkp = (float*)outp;
#pragma unroll
    for (int m = 0; m < MF; ++m) {
      int px0 = wv * WM + m * 16 + rq * 4;
#pragma unroll
      for (int n = 0; n < NF; ++n) {
        int o = n * 16 + ncol;
        if (o < 25) {
          float be = bias[o];
#pragma unroll
          for (int r = 0; r < 4; ++r)
            wkp[(pixb + px0 + r) * 25 + o] = acc[m][n][r] + be;
        }
      }
    }
  }
}

// ---------------- t1 = relu(bn(conv1x1(xh, w1)))  (64ch out, 64x64) ---------
__global__ __launch_bounds__(256) void k_t1(
    const float* __restrict__ xh, const float* __restrict__ w1,
    const float* __restrict__ g, const float* __restrict__ bb,
    float* __restrict__ t1) {
  int t = threadIdx.x;
  int o = t & 63, ps = t >> 6;
  int p0 = blockIdx.x * 16 + ps * 4;  // over B*4096
  const float* ip = xh + (size_t)p0 * 128;
  const float* wp = w1 + o * 128;
  float a0 = 0, a1 = 0, a2 = 0, a3 = 0;
  for (int c = 0; c < 128; ++c) {
    float w = wp[c];
    a0 += w * ip[c];       a1 += w * ip[128 + c];
    a2 += w * ip[256 + c]; a3 += w * ip[384 + c];
  }
  float sc = g[o] * BN_INV, be = bb[o];
  t1[(size_t)(p0 + 0) * 64 + o] = fmaxf(a0 * sc + be, 0.f);
  t1[(size_t)(p0 + 1) * 64 + o] = fmaxf(a1 * sc + be, 0.f);
  t1[(size_t)(p0 + 2) * 64 + o] = fmaxf(a2 * sc + be, 0.f);
  t1[(size_t)(p0 + 3) * 64 + o] = fmaxf(a3 * sc + be, 0.f);
}

// ------ bilinear up 64->128 of t1 (64ch) -> xcat_pad bf16 ch 0..63 ----------
__global__ __launch_bounds__(256) void k_up64_pad(const float* __restrict__ in,
                                                  u16* __restrict__ pad) {
  int t = threadIdx.x;
  int cp = (t & 31) * 2;
  int sub = t >> 5;                  // 8 px/block
  int g = blockIdx.x * 8 + sub;      // B*16384
  int b = g >> 14, pp = g & 16383;
  int oy = pp >> 7, ox = pp & 127;
  const float S = 63.0f / 127.0f;
  float fy = oy * S, fx = ox * S;
  int y0 = (int)fy, x0 = (int)fx;
  int y1 = min(y0 + 1, 63), x1 = min(x0 + 1, 63);
  float wy = fy - y0, wx = fx - x0;
  const float* base = in + (size_t)b * 4096 * 64;
  float2 v00 = *(const float2*)(base + ((y0 << 6) + x0) * 64 + cp);
  float2 v01 = *(const float2*)(base + ((y0 << 6) + x1) * 64 + cp);
  float2 v10 = *(const float2*)(base + ((y1 << 6) + x0) * 64 + cp);
  float2 v11 = *(const float2*)(base + ((y1 << 6) + x1) * 64 + cp);
  float r0 = (v00.x * (1.f - wx) + v01.x * wx) * (1.f - wy) +
             (v10.x * (1.f - wx) + v11.x * wx) * wy;
  float r1 = (v00.y * (1.f - wx) + v01.y * wx) * (1.f - wy) +
             (v10.y * (1.f - wx) + v11.y * wx) * wy;
  ushort2 o2; o2.x = f2bf(r0); o2.y = f2bf(r1);
  *(ushort2*)(pad + ((size_t)(b * 130 + oy + 1) * 130 + ox + 1) * 128 + cp) = o2;
}

// ---------------- SE: channel mean of xl ------------------------------------
__global__ __launch_bounds__(256) void k_semean(const float* __restrict__ xl,
                                                float* __restrict__ gmean) {
  int bid = blockIdx.x;  // B*64
  int b = bid >> 6, chunk = bid & 63;
  int t = threadIdx.x;
  int c = t & 127, sub = t >> 7;
  float s = 0.f;
  const float* base = xl + ((size_t)b * 16384 + chunk * 256) * 128;
  for (int p = sub; p < 256; p += 2) s += base[(size_t)p * 128 + c];
  __shared__ float lds[256];
  lds[t] = s;
  __syncthreads();
  if (t < 128) atomicAdd(&gmean[b * 128 + t], lds[t] + lds[t + 128]);
}

// ---------------- SE MLP + sigmoid + build per-batch effective w2 -----------
__global__ __launch_bounds__(128) void k_semlp(
    const float* __restrict__ gmean, const float* __restrict__ wf1,
    const float* __restrict__ bf1, const float* __restrict__ wf2,
    const float* __restrict__ bf2, const float* __restrict__ w2,
    float* __restrict__ weff) {
  int b = blockIdx.x;
  int t = threadIdx.x;  // 128
  __shared__ float m[128], hid[32], sg[128];
  m[t] = gmean[b * 128 + t] * (1.0f / 16384.0f);
  __syncthreads();
  if (t < 32) {
    float a = 0.f;
    for (int c = 0; c < 128; ++c) a += wf1[t * 128 + c] * m[c];
    hid[t] = fmaxf(a + bf1[t], 0.f);
  }
  __syncthreads();
  {
    float a = 0.f;
    for (int r = 0; r < 32; ++r) a += wf2[t * 32 + r] * hid[r];
    a += bf2[t];
    sg[t] = 1.f / (1.f + expf(-a));
  }
  __syncthreads();
  for (int o = 0; o < 64; ++o) {
    weff[((size_t)b * 64 + o) * 128 + t] =
        w2[o * 256 + t] * sg[t] + w2[o * 256 + 128 + t];
  }
}

// ------ x2 = relu(bn(weff_b . xl)) -> xcat_pad bf16 ch 64..127 ---------------
__global__ __launch_bounds__(256) void k_x2_pad(
    const float* __restrict__ xl, const float* __restrict__ weff,
    const float* __restrict__ g, const float* __restrict__ bb,
    u16* __restrict__ pad) {
  int t = threadIdx.x;
  int o = t & 63, ps = t >> 6;
  int p0 = blockIdx.x * 16 + ps * 4;  // over B*16384
  int b = p0 >> 14;
  int pp = p0 & 16383;
  int y = pp >> 7, x0 = pp & 127;
  const float* ip = xl + (size_t)p0 * 128;
  const float* wp = weff + ((size_t)b * 64 + o) * 128;
  float a0 = 0, a1 = 0, a2 = 0, a3 = 0;
  for (int c = 0; c < 128; ++c) {
    float w = wp[c];
    a0 += w * ip[c];       a1 += w * ip[128 + c];
    a2 += w * ip[256 + c]; a3 += w * ip[384 + c];
  }
  float sc = g[o] * BN_INV, be = bb[o];
  size_t rb = (size_t)(b * 130 + y + 1) * 130;
  pad[(rb + x0 + 1) * 128 + 64 + o] = f2bf(fmaxf(a0 * sc + be, 0.f));
  pad[(rb + x0 + 2) * 128 + 64 + o] = f2bf(fmaxf(a1 * sc + be, 0.f));
  pad[(rb + x0 + 3) * 128 + 64 + o] = f2bf(fmaxf(a2 * sc + be, 0.f));
  pad[(rb + x0 + 4) * 128 + 64 + o] = f2bf(fmaxf(a3 * sc + be, 0.f));
}

// ------ xh fp32 NHWC -> padded bf16 [B][66][66][128] ------------------------
__global__ __launch_bounds__(256) void k_xh2pad(const float* __restrict__ xh,
                                                u16* __restrict__ xhp) {
  int idx = blockIdx.x * 256 + threadIdx.x;  // 4*4096*16
  int c0 = (idx & 15) * 8;
  int p = idx >> 4;
  int b = p >> 12, pp = p & 4095;
  int y = pp >> 6, x = pp & 63;
  const float* s = xh + (size_t)p * 128 + c0;
  ushort8 o;
#pragma unroll
  for (int j = 0; j < 8; ++j) o[j] = f2bf(s[j]);
  *(ushort8*)(xhp + ((size_t)(b * 66 + y + 1) * 66 + (x + 1)) * 128 + c0) = o;
}

// ------ xl fp32 NHWC -> padded bf16 wo1-input ch 128..255 --------------------
__global__ __launch_bounds__(256) void k_xl2pad(const float* __restrict__ xl,
                                                u16* __restrict__ pad) {
  int idx = blockIdx.x * 256 + threadIdx.x;  // 65536 px * 16 groups
  int c0 = (idx & 15) * 8;
  int p = idx >> 4;
  int b = p >> 14, pp = p & 16383;
  int y = pp >> 7, x = pp & 127;
  const float* s = xl + (size_t)p * 128 + c0;
  ushort8 o;
#pragma unroll
  for (int j = 0; j < 8; ++j) o[j] = f2bf(s[j]);
  *(ushort8*)(pad + ((size_t)(b * 130 + y + 1) * 130 + (x + 1)) * 256 + 128 + c0) = o;
}

// ---------------- softmax over 25 channels ----------------------------------
__global__ __launch_bounds__(256) void k_softmax25(float* __restrict__ wk) {
  int g = blockIdx.x * 256 + threadIdx.x;  // B*16384
  float* p = wk + (size_t)g * 25;
  float mx = p[0];
#pragma unroll
  for (int i = 1; i < 25; ++i) mx = fmaxf(mx, p[i]);
  float e[25];
  float s = 0.f;
#pragma unroll
  for (int i = 0; i < 25; ++i) {
    e[i] = expf(p[i] - mx);
    s += e[i];
  }
  float inv = 1.f / s;
#pragma unroll
  for (int i = 0; i < 25; ++i) p[i] = e[i] * inv;
}

// ------ bilinear up 64->128 of xr (bf16,128ch) -> xup bf16 -------------------
__global__ __launch_bounds__(256) void k_up128_bf(
    const u16* __restrict__ in, u16* __restrict__ outb) {
  int t = threadIdx.x;
  int cp = (t & 63) * 2;
  int sub = t >> 6;                  // 4 px/block
  int g = blockIdx.x * 4 + sub;      // B*16384
  int b = g >> 14, pp = g & 16383;
  int oy = pp >> 7, ox = pp & 127;
  const float S = 63.0f / 127.0f;
  float fy = oy * S, fx = ox * S;
  int y0 = (int)fy, x0 = (int)fx;
  int y1 = min(y0 + 1, 63), x1 = min(x0 + 1, 63);
  float wy = fy - y0, wx = fx - x0;
  const u16* base = in + (size_t)b * 4096 * 128;
  const u16* p00 = base + ((y0 << 6) + x0) * 128 + cp;
  const u16* p01 = base + ((y0 << 6) + x1) * 128 + cp;
  const u16* p10 = base + ((y1 << 6) + x0) * 128 + cp;
  const u16* p11 = base + ((y1 << 6) + x1) * 128 + cp;
  ushort2 o2;
  u16 r[2];
#pragma unroll
  for (int j = 0; j < 2; ++j) {
    float top = bf2f(p00[j]) * (1.f - wx) + bf2f(p01[j]) * wx;
    float bot = bf2f(p10[j]) * (1.f - wx) + bf2f(p11[j]) * wx;
    r[j] = f2bf(top * (1.f - wy) + bot * wy);
  }
  o2.x = r[0]; o2.y = r[1];
  *(ushort2*)(outb + (size_t)g * 128 + cp) = o2;
}

// ------ CARAFE reassembly (bf16 in) -> wo1-input pad ch 0..127 ---------------
__global__ __launch_bounds__(256) void k_carafe_bf(
    const u16* __restrict__ xup, const float* __restrict__ wk,
    u16* __restrict__ pad) {
  int t = threadIdx.x;
  int cp = (t & 63) * 2;
  int sub = t >> 6;                  // 4 px/block
  int g = blockIdx.x * 4 + sub;
  int b = g >> 14, pp = g & 16383;
  int y = pp >> 7, x = pp & 127;
  __shared__ float wl[4][25];
  if (t < 100) wl[t / 25][t % 25] = wk[(size_t)(blockIdx.x * 4 + t / 25) * 25 + (t % 25)];
  __syncthreads();
  float a0 = 0.f, a1 = 0.f;
  const u16* base = xup + ((size_t)b << 14) * 128 + cp;
#pragma unroll
  for (int i = 0; i < 5; ++i) {
    int row = y + 2 * i - 4;
    if ((unsigned)row >= 128u) continue;
#pragma unroll
    for (int jj = 0; jj < 5; ++jj) {
      int col = x + 2 * jj - 4;
      if ((unsigned)col >= 128u) continue;
      const u16* q = base + (size_t)((row << 7) + col) * 128;
      float w = wl[sub][i * 5 + jj];
      a0 += w * bf2f(q[0]);
      a1 += w * bf2f(q[1]);
    }
  }
  ushort2 o2; o2.x = f2bf(a0); o2.y = f2bf(a1);
  *(ushort2*)(pad + ((size_t)(b * 130 + y + 1) * 130 + (x + 1)) * 256 + cp) = o2;
}

// ------ wo2 1x1 MFMA: y1 bf16 x [128][128] -> out NCHW fp32, relu ------------
__global__ __launch_bounds__(256) void k_wo2_mfma(
    const u16* __restrict__ y1, const u16* __restrict__ wb,
    const float* __restrict__ bb, float* __restrict__ out) {
  int t = threadIdx.x;
  int wv = t >> 6, l = t & 63;
  int blk = blockIdx.x;  // 1024
  int b = blk >> 8, rr = blk & 255;
  int y = rr >> 1;
  int xseg = (rr & 1) << 6;
  int m0 = xseg + wv * 16;
  int xc = m0 + (l & 15);
  int kg = l >> 4;
  const u16* abase =
      y1 + ((size_t)((b << 14) + (y << 7) + xc)) * 128 + kg * 8;
  const u16* bbase = wb + (size_t)(l & 15) * 128 + kg * 8;
  f32x4 acc[8];
#pragma unroll
  for (int i = 0; i < 8; ++i) acc[i] = (f32x4){0.f, 0.f, 0.f, 0.f};
#pragma unroll
  for (int cc = 0; cc < 4; ++cc) {
    bf16x8 a = *(const bf16x8*)(abase + cc * 32);
#pragma unroll
    for (int nf = 0; nf < 8; ++nf) {
      bf16x8 bfr = *(const bf16x8*)(bbase + nf * 16 * 128 + cc * 32);
      acc[nf] = __builtin_amdgcn_mfma_f32_16x16x32_bf16(a, bfr, acc[nf], 0, 0, 0);
    }
  }
  int prow = m0 + (l >> 4) * 4;
  int ncol = l & 15;
#pragma unroll
  for (int nf = 0; nf < 8; ++nf) {
    int o = nf * 16 + ncol;
    float be = bb[o];
    f32x4 r;
#pragma unroll
    for (int k = 0; k < 4; ++k) r[k] = fmaxf(acc[nf][k] + be, 0.f);
    *(f32x4*)(out + (((size_t)(b * 128 + o) * 128 + y) << 7) + prow) = r;
  }
}

extern "C" void kernel_launch(void* const* d_in, const int* in_sizes, int n_in,
                              void* d_out, int out_size, void* d_ws,
                              size_t ws_size, hipStream_t stream) {
  const float* x_h  = (const float*)d_in[0];
  const float* x_l  = (const float*)d_in[1];
  const float* wr   = (const float*)d_in[2];
  const float* wr_g = (const float*)d_in[3];
  const float* wr_b = (const float*)d_in[4];
  const float* w1   = (const float*)d_in[5];
  const float* w1_g = (const float*)d_in[6];
  const float* w1_b = (const float*)d_in[7];
  const float* w2   = (const float*)d_in[8];
  const float* w2_g = (const float*)d_in[9];
  const float* w2_b = (const float*)d_in[10];
  const float* we   = (const float*)d_in[11];
  const float* we_g = (const float*)d_in[12];
  const float* we_b = (const float*)d_in[13];
  const float* wf1  = (const float*)d_in[14];
  const float* bf1  = (const float*)d_in[15];
  const float* wf2  = (const float*)d_in[16];
  const float* bf2  = (const float*)d_in[17];
  const float* wo1  = (const float*)d_in[18];
  const float* wo1_g= (const float*)d_in[19];
  const float* wo1_b= (const float*)d_in[20];
  const float* wo2  = (const float*)d_in[21];
  const float* wo2_g= (const float*)d_in[22];
  const float* wo2_b= (const float*)d_in[23];
  float* out = (float*)d_out;

  float* ws = (float*)d_ws;
  // layout (f32 offsets), total 20,141,568 f32 = 80.57 MB
  u16* pad      = (u16*)ws;                  // [4][130][130][256] bf16
  u16* xcat_pad = (u16*)(ws + 8652800);      // [4][130][130][128] bf16
  u16* xup      = xcat_pad;                  // reuse after we_mfma
  float* wkb   = ws + 12979200;              // 1,638,400 f32
  float* t1    = ws + 14617600;              // 1,048,576 f32
  u16* xr = (u16*)t1;                        // reuse after up64
  float* y1reg = ws + 15666176;              // 4,194,304 f32 region
  u16* y1     = (u16*)y1reg;                 // 8,388,608 bf16 (late)
  u16* xh_pad = (u16*)y1reg;                 // 2,230,272 bf16 (early)
  float* gmean = ws + 19860480;              // 512
  float* weff  = gmean + 512;                // 32,768
  u16* wr_bf = (u16*)(weff + 32768);         // 147,456 bf16
  u16* we_bf = (u16*)(weff + 32768 + 73728); // 36,864 bf16
  u16* wo1bf = (u16*)(weff + 32768 + 73728 + 18432);           // 294,912 bf16
  u16* wo2bf = (u16*)(weff + 32768 + 73728 + 18432 + 147456);  // 16,384 bf16

  hipMemsetAsync(gmean, 0, 512 * sizeof(float), stream);
  hipMemsetAsync(pad, 0, (size_t)4 * 130 * 130 * 256 * 2, stream);
  hipMemsetAsync(xcat_pad, 0, (size_t)4 * 130 * 130 * 128 * 2, stream);
  hipMemsetAsync(xh_pad, 0, (size_t)4 * 66 * 66 * 128 * 2, stream);

  k_repack_bf<<<576, 256, 0, stream>>>(wr, wr_g, wr_bf, 128, 128, 128, 9);
  k_repack_bf<<<144, 256, 0, stream>>>(we, we_g, we_bf, 25, 128, 32, 9);
  k_repack_bf<<<1152, 256, 0, stream>>>(wo1, wo1_g, wo1bf, 128, 256, 128, 9);
  k_repack_bf<<<64, 256, 0, stream>>>(wo2, wo2_g, wo2bf, 128, 128, 128, 1);

  k_t1<<<1024, 256, 0, stream>>>(x_h, w1, w1_g, w1_b, t1);
  k_up64_pad<<<8192, 256, 0, stream>>>(t1, xcat_pad);          // ch 0..63
  k_semean<<<256, 256, 0, stream>>>(x_l, gmean);
  k_semlp<<<4, 128, 0, stream>>>(gmean, wf1, bf1, wf2, bf2, w2, weff);
  k_x2_pad<<<4096, 256, 0, stream>>>(x_l, weff, w2_g, w2_b, xcat_pad);  // ch 64..127
  k_xh2pad<<<1024, 256, 0, stream>>>(x_h, xh_pad);
  k_xl2pad<<<4096, 256, 0, stream>>>(x_l, pad);

  // we: PADW=130, CIN=128, NOUT(pad)=32, NB=32, TILE_M=128, EPI=1 (fp32, 25ch)
  k_conv_mfma<130, 128, 32, 32, 128, 1><<<512, 256, 0, stream>>>(
      xcat_pad, we_bf, we_b, wkb);
  k_softmax25<<<256, 256, 0, stream>>>(wkb);
  // wr: PADW=66, CIN=128, NOUT=128, NB=64 (2 segs), TILE_M=64, EPI=0 (bf16+relu)
  k_conv_mfma<66, 128, 128, 64, 64, 0><<<512, 256, 0, stream>>>(
      xh_pad, wr_bf, wr_b, xr);
  k_up128_bf<<<16384, 256, 0, stream>>>(xr, xup);              // xcat_pad now dead
  k_carafe_bf<<<16384, 256, 0, stream>>>(xup, wkb, pad);       // X -> pad ch 0..127
  // wo1: PADW=130, CIN=256, NOUT=128, NB=128, TILE_M=128, EPI=0 (bf16+relu)
  k_conv_mfma<130, 256, 128, 128, 128, 0><<<512, 256, 0, stream>>>(
      pad, wo1bf, wo1_b, y1);                                  // xh_pad dead
  k_wo2_mfma<<<1024, 256, 0, stream>>>(y1, wo2bf, wo2_b, out);
}

// Round 6
// 410.783 us; speedup vs baseline: 7.7853x; 1.0002x over previous
//
#include <hip/hip_runtime.h>
#include <hip/hip_bf16.h>

#define BN_INV 0.99999500003749968f  // 1/sqrt(1+1e-5)

typedef __attribute__((ext_vector_type(8))) short bf16x8;
typedef __attribute__((ext_vector_type(4))) float f32x4;
typedef __attribute__((ext_vector_type(8))) unsigned short ushort8;
typedef unsigned short u16;

__device__ inline u16 f2bf(float f) {
  union { float f; unsigned int u; } v;
  v.f = f;
  unsigned int r = v.u + 0x7FFFu + ((v.u >> 16) & 1u);
  return (u16)(r >> 16);
}
__device__ inline float bf2f(u16 u) {
  union { unsigned int u; float f; } v;
  v.u = ((unsigned int)u) << 16;
  return v.f;
}

// async global->LDS, 16B per lane, dest = uniform base + lane*16
#define GLOAD_LDS16(g, l)                                              \
  __builtin_amdgcn_global_load_lds(                                    \
      (const __attribute__((address_space(1))) unsigned int*)(g),      \
      (__attribute__((address_space(3))) unsigned int*)(l), 16, 0, 0)

// ------ generic weight repack: OIHW -> bf16 [tap][o(OPAD)][c], bn folded ----
__global__ __launch_bounds__(256) void k_repack_bf(
    const float* __restrict__ w, const float* __restrict__ g,
    u16* __restrict__ out, int Cout, int Cin, int OPAD, int TAPS) {
  int idx = blockIdx.x * 256 + threadIdx.x;
  int total = TAPS * Cin * OPAD;
  if (idx >= total) return;
  int c = idx % Cin;
  int o = (idx / Cin) % OPAD;
  int tap = idx / (Cin * OPAD);
  float v = 0.f;
  if (o < Cout) v = w[(o * Cin + c) * TAPS + tap] * g[o] * BN_INV;
  out[idx] = f2bf(v);
}

// ================= tiled implicit-GEMM 3x3 conv, bf16 MFMA ==================
// pad: [B][PADW][PADW][CIN] bf16, zero ring. wb: [9][NOUT][CIN] bf16 (bn folded)
// block = 4 waves, tile = TILE_M px (one row chunk) x NB couts.
// K-steps: 9 taps x CIN/64. LDS A[TILE_M][64], B[NB][64], double-buffered.
// XOR swizzle: 16B slot ^= (row&7) (pre-swizzled global src, swizzled ds_read).
template <int PADW, int CIN, int NOUT, int NB, int TILE_M, int EPI>
__global__ __launch_bounds__(256, 2) void k_conv_mfma(
    const u16* __restrict__ pad, const u16* __restrict__ wb,
    const float* __restrict__ bias, void* __restrict__ outp) {
  constexpr int H = PADW - 2;          // output H == W
  constexpr int NSEG = NOUT / NB;
  constexpr int KQ = CIN / 64;
  constexpr int NSTEPS = 9 * KQ;
  constexpr int WM = TILE_M / 4;       // px per wave
  constexpr int MF = WM / 16;
  constexpr int NF = NB / 16;
  __shared__ alignas(16) u16 As[2][TILE_M * 64];
  __shared__ alignas(16) u16 Bs[2][NB * 64];

  int tid = threadIdx.x, wv = tid >> 6, l = tid & 63;
  int bid = blockIdx.x;
  int ns = (NSEG > 1) ? (bid % NSEG) : 0;
  int row = (NSEG > 1) ? (bid / NSEG) : bid;
  int b = row / H, y = row % H;
  const u16* pbat = pad + (size_t)b * PADW * PADW * CIN;

  auto stage = [&](int t, int bufi) {
    int tap = t / KQ;
    int ch0 = (t % KQ) * 64;
    int ky = tap / 3, kx = tap % 3;
    const u16* arow = pbat + ((size_t)(y + ky) * PADW + kx) * CIN + ch0;
#pragma unroll
    for (int j = 0; j < TILE_M * 8 / 256; ++j) {
      int q = j * 256 + tid;
      int px = q >> 3;
      int sl = (q & 7) ^ (px & 7);
      GLOAD_LDS16(arow + (size_t)px * CIN + sl * 8,
                  (char*)&As[bufi][0] + (size_t)(j * 256 + (tid & ~63)) * 16);
    }
    const u16* brow = wb + ((size_t)tap * NOUT + ns * NB) * CIN + ch0;
#pragma unroll
    for (int j = 0; j < NB * 8 / 256; ++j) {
      int q = j * 256 + tid;
      int co = q >> 3;
      int sl = (q & 7) ^ (co & 7);
      GLOAD_LDS16(brow + (size_t)co * CIN + sl * 8,
                  (char*)&Bs[bufi][0] + (size_t)(j * 256 + (tid & ~63)) * 16);
    }
  };

  f32x4 acc[MF][NF];
#pragma unroll
  for (int m = 0; m < MF; ++m)
#pragma unroll
    for (int n = 0; n < NF; ++n) acc[m][n] = (f32x4){0.f, 0.f, 0.f, 0.f};

  stage(0, 0);
  for (int t = 0; t < NSTEPS; ++t) {
    __syncthreads();
    if (t + 1 < NSTEPS) stage(t + 1, (t + 1) & 1);
    const u16* Ab = &As[t & 1][0];
    const u16* Bb = &Bs[t & 1][0];
    bf16x8 Bf[2][NF];
#pragma unroll
    for (int kf = 0; kf < 2; ++kf)
#pragma unroll
      for (int n = 0; n < NF; ++n) {
        int co = n * 16 + (l & 15);
        int sl = (kf * 4 + (l >> 4)) ^ (co & 7);
        Bf[kf][n] = *(const bf16x8*)((const char*)Bb + co * 128 + sl * 16);
      }
#pragma unroll
    for (int m = 0; m < MF; ++m) {
      int px = wv * WM + m * 16 + (l & 15);
      int s0 = (l >> 4) ^ (px & 7);
      int s1 = (4 + (l >> 4)) ^ (px & 7);
      bf16x8 a0 = *(const bf16x8*)((const char*)Ab + px * 128 + s0 * 16);
      bf16x8 a1 = *(const bf16x8*)((const char*)Ab + px * 128 + s1 * 16);
#pragma unroll
      for (int n = 0; n < NF; ++n) {
        acc[m][n] = __builtin_amdgcn_mfma_f32_16x16x32_bf16(a0, Bf[0][n], acc[m][n], 0, 0, 0);
        acc[m][n] = __builtin_amdgcn_mfma_f32_16x16x32_bf16(a1, Bf[1][n], acc[m][n], 0, 0, 0);
      }
    }
  }

  int ncol = l & 15, rq = l >> 4;
  size_t pixb = ((size_t)b * H + y) * H;
  if (EPI == 0) {  // bf16 NHWC (stride NOUT), bias + relu
    u16* ob = (u16*)outp;
#pragma unroll
    for (int m = 0; m < MF; ++m) {
      int px0 = wv * WM + m * 16 + rq * 4;
#pragma unroll
      for (int n = 0; n < NF; ++n) {
        int o = ns * NB + n * 16 + ncol;
        float be = bias[o];
#pragma unroll
        for (int r = 0; r < 4; ++r)
          ob[(pixb + px0 + r) * NOUT + o] = f2bf(fmaxf(acc[m][n][r] + be, 0.f));
      }
    }
  } else {  // EPI==1: fp32, 25-channel (we), bias only
    float* wkp = (float*)outp;
#pragma unroll
    for (int m = 0; m < MF; ++m) {
      int px0 = wv * WM + m * 16 + rq * 4;
#pragma unroll
      for (int n = 0; n < NF; ++n) {
        int o = n * 16 + ncol;
        if (o < 25) {
          float be = bias[o];
#pragma unroll
          for (int r = 0; r < 4; ++r)
            wkp[(pixb + px0 + r) * 25 + o] = acc[m][n][r] + be;
        }
      }
    }
  }
}

// ---------------- t1 = relu(bn(conv1x1(xh, w1)))  (64ch out, 64x64) ---------
__global__ __launch_bounds__(256) void k_t1(
    const float* __restrict__ xh, const float* __restrict__ w1,
    const float* __restrict__ g, const float* __restrict__ bb,
    float* __restrict__ t1) {
  int t = threadIdx.x;
  int o = t & 63, ps = t >> 6;
  int p0 = blockIdx.x * 16 + ps * 4;  // over B*4096
  const float* ip = xh + (size_t)p0 * 128;
  const float* wp = w1 + o * 128;
  float a0 = 0, a1 = 0, a2 = 0, a3 = 0;
  for (int c = 0; c < 128; ++c) {
    float w = wp[c];
    a0 += w * ip[c];       a1 += w * ip[128 + c];
    a2 += w * ip[256 + c]; a3 += w * ip[384 + c];
  }
  float sc = g[o] * BN_INV, be = bb[o];
  t1[(size_t)(p0 + 0) * 64 + o] = fmaxf(a0 * sc + be, 0.f);
  t1[(size_t)(p0 + 1) * 64 + o] = fmaxf(a1 * sc + be, 0.f);
  t1[(size_t)(p0 + 2) * 64 + o] = fmaxf(a2 * sc + be, 0.f);
  t1[(size_t)(p0 + 3) * 64 + o] = fmaxf(a3 * sc + be, 0.f);
}

// ------ bilinear up 64->128 of t1 (64ch) -> xcat_pad bf16 ch 0..63 ----------
__global__ __launch_bounds__(256) void k_up64_pad(const float* __restrict__ in,
                                                  u16* __restrict__ pad) {
  int t = threadIdx.x;
  int cp = (t & 31) * 2;
  int sub = t >> 5;                  // 8 px/block
  int g = blockIdx.x * 8 + sub;      // B*16384
  int b = g >> 14, pp = g & 16383;
  int oy = pp >> 7, ox = pp & 127;
  const float S = 63.0f / 127.0f;
  float fy = oy * S, fx = ox * S;
  int y0 = (int)fy, x0 = (int)fx;
  int y1 = min(y0 + 1, 63), x1 = min(x0 + 1, 63);
  float wy = fy - y0, wx = fx - x0;
  const float* base = in + (size_t)b * 4096 * 64;
  float2 v00 = *(const float2*)(base + ((y0 << 6) + x0) * 64 + cp);
  float2 v01 = *(const float2*)(base + ((y0 << 6) + x1) * 64 + cp);
  float2 v10 = *(const float2*)(base + ((y1 << 6) + x0) * 64 + cp);
  float2 v11 = *(const float2*)(base + ((y1 << 6) + x1) * 64 + cp);
  float r0 = (v00.x * (1.f - wx) + v01.x * wx) * (1.f - wy) +
             (v10.x * (1.f - wx) + v11.x * wx) * wy;
  float r1 = (v00.y * (1.f - wx) + v01.y * wx) * (1.f - wy) +
             (v10.y * (1.f - wx) + v11.y * wx) * wy;
  ushort2 o2; o2.x = f2bf(r0); o2.y = f2bf(r1);
  *(ushort2*)(pad + ((size_t)(b * 130 + oy + 1) * 130 + ox + 1) * 128 + cp) = o2;
}

// ---------------- SE: channel mean of xl ------------------------------------
__global__ __launch_bounds__(256) void k_semean(const float* __restrict__ xl,
                                                float* __restrict__ gmean) {
  int bid = blockIdx.x;  // B*64
  int b = bid >> 6, chunk = bid & 63;
  int t = threadIdx.x;
  int c = t & 127, sub = t >> 7;
  float s = 0.f;
  const float* base = xl + ((size_t)b * 16384 + chunk * 256) * 128;
  for (int p = sub; p < 256; p += 2) s += base[(size_t)p * 128 + c];
  __shared__ float lds[256];
  lds[t] = s;
  __syncthreads();
  if (t < 128) atomicAdd(&gmean[b * 128 + t], lds[t] + lds[t + 128]);
}

// ---------------- SE MLP + sigmoid + build per-batch effective w2 -----------
__global__ __launch_bounds__(128) void k_semlp(
    const float* __restrict__ gmean, const float* __restrict__ wf1,
    const float* __restrict__ bf1, const float* __restrict__ wf2,
    const float* __restrict__ bf2, const float* __restrict__ w2,
    float* __restrict__ weff) {
  int b = blockIdx.x;
  int t = threadIdx.x;  // 128
  __shared__ float m[128], hid[32], sg[128];
  m[t] = gmean[b * 128 + t] * (1.0f / 16384.0f);
  __syncthreads();
  if (t < 32) {
    float a = 0.f;
    for (int c = 0; c < 128; ++c) a += wf1[t * 128 + c] * m[c];
    hid[t] = fmaxf(a + bf1[t], 0.f);
  }
  __syncthreads();
  {
    float a = 0.f;
    for (int r = 0; r < 32; ++r) a += wf2[t * 32 + r] * hid[r];
    a += bf2[t];
    sg[t] = 1.f / (1.f + expf(-a));
  }
  __syncthreads();
  for (int o = 0; o < 64; ++o) {
    weff[((size_t)b * 64 + o) * 128 + t] =
        w2[o * 256 + t] * sg[t] + w2[o * 256 + 128 + t];
  }
}

// ------ x2 = relu(bn(weff_b . xl)) -> xcat_pad bf16 ch 64..127 ---------------
__global__ __launch_bounds__(256) void k_x2_pad(
    const float* __restrict__ xl, const float* __restrict__ weff,
    const float* __restrict__ g, const float* __restrict__ bb,
    u16* __restrict__ pad) {
  int t = threadIdx.x;
  int o = t & 63, ps = t >> 6;
  int p0 = blockIdx.x * 16 + ps * 4;  // over B*16384
  int b = p0 >> 14;
  int pp = p0 & 16383;
  int y = pp >> 7, x0 = pp & 127;
  const float* ip = xl + (size_t)p0 * 128;
  const float* wp = weff + ((size_t)b * 64 + o) * 128;
  float a0 = 0, a1 = 0, a2 = 0, a3 = 0;
  for (int c = 0; c < 128; ++c) {
    float w = wp[c];
    a0 += w * ip[c];       a1 += w * ip[128 + c];
    a2 += w * ip[256 + c]; a3 += w * ip[384 + c];
  }
  float sc = g[o] * BN_INV, be = bb[o];
  size_t rb = (size_t)(b * 130 + y + 1) * 130;
  pad[(rb + x0 + 1) * 128 + 64 + o] = f2bf(fmaxf(a0 * sc + be, 0.f));
  pad[(rb + x0 + 2) * 128 + 64 + o] = f2bf(fmaxf(a1 * sc + be, 0.f));
  pad[(rb + x0 + 3) * 128 + 64 + o] = f2bf(fmaxf(a2 * sc + be, 0.f));
  pad[(rb + x0 + 4) * 128 + 64 + o] = f2bf(fmaxf(a3 * sc + be, 0.f));
}

// ------ xh fp32 NHWC -> padded bf16 [B][66][66][128] ------------------------
__global__ __launch_bounds__(256) void k_xh2pad(const float* __restrict__ xh,
                                                u16* __restrict__ xhp) {
  int idx = blockIdx.x * 256 + threadIdx.x;  // 4*4096*16
  int c0 = (idx & 15) * 8;
  int p = idx >> 4;
  int b = p >> 12, pp = p & 4095;
  int y = pp >> 6, x = pp & 63;
  const float* s = xh + (size_t)p * 128 + c0;
  ushort8 o;
#pragma unroll
  for (int j = 0; j < 8; ++j) o[j] = f2bf(s[j]);
  *(ushort8*)(xhp + ((size_t)(b * 66 + y + 1) * 66 + (x + 1)) * 128 + c0) = o;
}

// ------ xl fp32 NHWC -> padded bf16 wo1-input ch 128..255 --------------------
__global__ __launch_bounds__(256) void k_xl2pad(const float* __restrict__ xl,
                                                u16* __restrict__ pad) {
  int idx = blockIdx.x * 256 + threadIdx.x;  // 65536 px * 16 groups
  int c0 = (idx & 15) * 8;
  int p = idx >> 4;
  int b = p >> 14, pp = p & 16383;
  int y = pp >> 7, x = pp & 127;
  const float* s = xl + (size_t)p * 128 + c0;
  ushort8 o;
#pragma unroll
  for (int j = 0; j < 8; ++j) o[j] = f2bf(s[j]);
  *(ushort8*)(pad + ((size_t)(b * 130 + y + 1) * 130 + (x + 1)) * 256 + 128 + c0) = o;
}

// ---------------- softmax over 25 channels ----------------------------------
__global__ __launch_bounds__(256) void k_softmax25(float* __restrict__ wk) {
  int g = blockIdx.x * 256 + threadIdx.x;  // B*16384
  float* p = wk + (size_t)g * 25;
  float mx = p[0];
#pragma unroll
  for (int i = 1; i < 25; ++i) mx = fmaxf(mx, p[i]);
  float e[25];
  float s = 0.f;
#pragma unroll
  for (int i = 0; i < 25; ++i) {
    e[i] = expf(p[i] - mx);
    s += e[i];
  }
  float inv = 1.f / s;
#pragma unroll
  for (int i = 0; i < 25; ++i) p[i] = e[i] * inv;
}

// ------ bilinear up 64->128 of xr (bf16,128ch) -> xup bf16 -------------------
__global__ __launch_bounds__(256) void k_up128_bf(
    const u16* __restrict__ in, u16* __restrict__ outb) {
  int t = threadIdx.x;
  int cp = (t & 63) * 2;
  int sub = t >> 6;                  // 4 px/block
  int g = blockIdx.x * 4 + sub;      // B*16384
  int b = g >> 14, pp = g & 16383;
  int oy = pp >> 7, ox = pp & 127;
  const float S = 63.0f / 127.0f;
  float fy = oy * S, fx = ox * S;
  int y0 = (int)fy, x0 = (int)fx;
  int y1 = min(y0 + 1, 63), x1 = min(x0 + 1, 63);
  float wy = fy - y0, wx = fx - x0;
  const u16* base = in + (size_t)b * 4096 * 128;
  const u16* p00 = base + ((y0 << 6) + x0) * 128 + cp;
  const u16* p01 = base + ((y0 << 6) + x1) * 128 + cp;
  const u16* p10 = base + ((y1 << 6) + x0) * 128 + cp;
  const u16* p11 = base + ((y1 << 6) + x1) * 128 + cp;
  ushort2 o2;
  u16 r[2];
#pragma unroll
  for (int j = 0; j < 2; ++j) {
    float top = bf2f(p00[j]) * (1.f - wx) + bf2f(p01[j]) * wx;
    float bot = bf2f(p10[j]) * (1.f - wx) + bf2f(p11[j]) * wx;
    r[j] = f2bf(top * (1.f - wy) + bot * wy);
  }
  o2.x = r[0]; o2.y = r[1];
  *(ushort2*)(outb + (size_t)g * 128 + cp) = o2;
}

// ------ CARAFE reassembly (bf16 in) -> wo1-input pad ch 0..127 ---------------
__global__ __launch_bounds__(256) void k_carafe_bf(
    const u16* __restrict__ xup, const float* __restrict__ wk,
    u16* __restrict__ pad) {
  int t = threadIdx.x;
  int cp = (t & 63) * 2;
  int sub = t >> 6;                  // 4 px/block
  int g = blockIdx.x * 4 + sub;
  int b = g >> 14, pp = g & 16383;
  int y = pp >> 7, x = pp & 127;
  __shared__ float wl[4][25];
  if (t < 100) wl[t / 25][t % 25] = wk[(size_t)(blockIdx.x * 4 + t / 25) * 25 + (t % 25)];
  __syncthreads();
  float a0 = 0.f, a1 = 0.f;
  const u16* base = xup + ((size_t)b << 14) * 128 + cp;
#pragma unroll
  for (int i = 0; i < 5; ++i) {
    int row = y + 2 * i - 4;
    if ((unsigned)row >= 128u) continue;
#pragma unroll
    for (int jj = 0; jj < 5; ++jj) {
      int col = x + 2 * jj - 4;
      if ((unsigned)col >= 128u) continue;
      const u16* q = base + (size_t)((row << 7) + col) * 128;
      float w = wl[sub][i * 5 + jj];
      a0 += w * bf2f(q[0]);
      a1 += w * bf2f(q[1]);
    }
  }
  ushort2 o2; o2.x = f2bf(a0); o2.y = f2bf(a1);
  *(ushort2*)(pad + ((size_t)(b * 130 + y + 1) * 130 + (x + 1)) * 256 + cp) = o2;
}

// ------ wo2 1x1 MFMA: y1 bf16 x [128][128] -> out NCHW fp32, relu ------------
__global__ __launch_bounds__(256) void k_wo2_mfma(
    const u16* __restrict__ y1, const u16* __restrict__ wb,
    const float* __restrict__ bb, float* __restrict__ out) {
  int t = threadIdx.x;
  int wv = t >> 6, l = t & 63;
  int blk = blockIdx.x;  // 1024
  int b = blk >> 8, rr = blk & 255;
  int y = rr >> 1;
  int xseg = (rr & 1) << 6;
  int m0 = xseg + wv * 16;
  int xc = m0 + (l & 15);
  int kg = l >> 4;
  const u16* abase =
      y1 + ((size_t)((b << 14) + (y << 7) + xc)) * 128 + kg * 8;
  const u16* bbase = wb + (size_t)(l & 15) * 128 + kg * 8;
  f32x4 acc[8];
#pragma unroll
  for (int i = 0; i < 8; ++i) acc[i] = (f32x4){0.f, 0.f, 0.f, 0.f};
#pragma unroll
  for (int cc = 0; cc < 4; ++cc) {
    bf16x8 a = *(const bf16x8*)(abase + cc * 32);
#pragma unroll
    for (int nf = 0; nf < 8; ++nf) {
      bf16x8 bfr = *(const bf16x8*)(bbase + nf * 16 * 128 + cc * 32);
      acc[nf] = __builtin_amdgcn_mfma_f32_16x16x32_bf16(a, bfr, acc[nf], 0, 0, 0);
    }
  }
  int prow = m0 + (l >> 4) * 4;
  int ncol = l & 15;
#pragma unroll
  for (int nf = 0; nf < 8; ++nf) {
    int o = nf * 16 + ncol;
    float be = bb[o];
    f32x4 r;
#pragma unroll
    for (int k = 0; k < 4; ++k) r[k] = fmaxf(acc[nf][k] + be, 0.f);
    *(f32x4*)(out + (((size_t)(b * 128 + o) * 128 + y) << 7) + prow) = r;
  }
}

extern "C" void kernel_launch(void* const* d_in, const int* in_sizes, int n_in,
                              void* d_out, int out_size, void* d_ws,
                              size_t ws_size, hipStream_t stream) {
  const float* x_h  = (const float*)d_in[0];
  const float* x_l  = (const float*)d_in[1];
  const float* wr   = (const float*)d_in[2];
  const float* wr_g = (const float*)d_in[3];
  const float* wr_b = (const float*)d_in[4];
  const float* w1   = (const float*)d_in[5];
  const float* w1_g = (const float*)d_in[6];
  const float* w1_b = (const float*)d_in[7];
  const float* w2   = (const float*)d_in[8];
  const float* w2_g = (const float*)d_in[9];
  const float* w2_b = (const float*)d_in[10];
  const float* we   = (const float*)d_in[11];
  const float* we_g = (const float*)d_in[12];
  const float* we_b = (const float*)d_in[13];
  const float* wf1  = (const float*)d_in[14];
  const float* bf1  = (const float*)d_in[15];
  const float* wf2  = (const float*)d_in[16];
  const float* bf2  = (const float*)d_in[17];
  const float* wo1  = (const float*)d_in[18];
  const float* wo1_g= (const float*)d_in[19];
  const float* wo1_b= (const float*)d_in[20];
  const float* wo2  = (const float*)d_in[21];
  const float* wo2_g= (const float*)d_in[22];
  const float* wo2_b= (const float*)d_in[23];
  float* out = (float*)d_out;

  float* ws = (float*)d_ws;
  // layout (f32 offsets), total 20,141,568 f32 = 80.57 MB
  u16* pad      = (u16*)ws;                  // [4][130][130][256] bf16
  u16* xcat_pad = (u16*)(ws + 8652800);      // [4][130][130][128] bf16
  u16* xup      = xcat_pad;                  // reuse after we_mfma
  float* wkb   = ws + 12979200;              // 1,638,400 f32
  float* t1    = ws + 14617600;              // 1,048,576 f32
  u16* xr = (u16*)t1;                        // reuse after up64
  float* y1reg = ws + 15666176;              // 4,194,304 f32 region
  u16* y1     = (u16*)y1reg;                 // 8,388,608 bf16 (late)
  u16* xh_pad = (u16*)y1reg;                 // 2,230,272 bf16 (early)
  float* gmean = ws + 19860480;              // 512
  float* weff  = gmean + 512;                // 32,768
  u16* wr_bf = (u16*)(weff + 32768);         // 147,456 bf16
  u16* we_bf = (u16*)(weff + 32768 + 73728); // 36,864 bf16
  u16* wo1bf = (u16*)(weff + 32768 + 73728 + 18432);           // 294,912 bf16
  u16* wo2bf = (u16*)(weff + 32768 + 73728 + 18432 + 147456);  // 16,384 bf16

  hipMemsetAsync(gmean, 0, 512 * sizeof(float), stream);
  hipMemsetAsync(pad, 0, (size_t)4 * 130 * 130 * 256 * 2, stream);
  hipMemsetAsync(xcat_pad, 0, (size_t)4 * 130 * 130 * 128 * 2, stream);
  hipMemsetAsync(xh_pad, 0, (size_t)4 * 66 * 66 * 128 * 2, stream);

  k_repack_bf<<<576, 256, 0, stream>>>(wr, wr_g, wr_bf, 128, 128, 128, 9);
  k_repack_bf<<<144, 256, 0, stream>>>(we, we_g, we_bf, 25, 128, 32, 9);
  k_repack_bf<<<1152, 256, 0, stream>>>(wo1, wo1_g, wo1bf, 128, 256, 128, 9);
  k_repack_bf<<<64, 256, 0, stream>>>(wo2, wo2_g, wo2bf, 128, 128, 128, 1);

  k_t1<<<1024, 256, 0, stream>>>(x_h, w1, w1_g, w1_b, t1);
  k_up64_pad<<<8192, 256, 0, stream>>>(t1, xcat_pad);          // ch 0..63
  k_semean<<<256, 256, 0, stream>>>(x_l, gmean);
  k_semlp<<<4, 128, 0, stream>>>(gmean, wf1, bf1, wf2, bf2, w2, weff);
  k_x2_pad<<<4096, 256, 0, stream>>>(x_l, weff, w2_g, w2_b, xcat_pad);  // ch 64..127
  k_xh2pad<<<1024, 256, 0, stream>>>(x_h, xh_pad);
  k_xl2pad<<<4096, 256, 0, stream>>>(x_l, pad);

  // we: PADW=130, CIN=128, NOUT(pad)=32, NB=32, TILE_M=128, EPI=1 (fp32, 25ch)
  k_conv_mfma<130, 128, 32, 32, 128, 1><<<512, 256, 0, stream>>>(
      xcat_pad, we_bf, we_b, wkb);
  k_softmax25<<<256, 256, 0, stream>>>(wkb);
  // wr: PADW=66, CIN=128, NOUT=128, NB=64 (2 segs), TILE_M=64, EPI=0 (bf16+relu)
  k_conv_mfma<66, 128, 128, 64, 64, 0><<<512, 256, 0, stream>>>(
      xh_pad, wr_bf, wr_b, xr);
  k_up128_bf<<<16384, 256, 0, stream>>>(xr, xup);              // xcat_pad now dead
  k_carafe_bf<<<16384, 256, 0, stream>>>(xup, wkb, pad);       // X -> pad ch 0..127
  // wo1: PADW=130, CIN=256, NOUT=128, NB=128, TILE_M=128, EPI=0 (bf16+relu)
  k_conv_mfma<130, 256, 128, 128, 128, 0><<<512, 256, 0, stream>>>(
      pad, wo1bf, wo1_b, y1);                                  // xh_pad dead
  k_wo2_mfma<<<1024, 256, 0, stream>>>(y1, wo2bf, wo2_b, out);
}

// Round 7
// 410.652 us; speedup vs baseline: 7.7877x; 1.0003x over previous
//
#include <hip/hip_runtime.h>
#include <hip/hip_bf16.h>

#define BN_INV 0.99999500003749968f  // 1/sqrt(1+1e-5)

typedef __attribute__((ext_vector_type(8))) short bf16x8;
typedef __attribute__((ext_vector_type(4))) float f32x4;
typedef __attribute__((ext_vector_type(8))) unsigned short ushort8;
typedef unsigned short u16;

__device__ inline u16 f2bf(float f) {
  union { float f; unsigned int u; } v;
  v.f = f;
  unsigned int r = v.u + 0x7FFFu + ((v.u >> 16) & 1u);
  return (u16)(r >> 16);
}
__device__ inline float bf2f(u16 u) {
  union { unsigned int u; float f; } v;
  v.u = ((unsigned int)u) << 16;
  return v.f;
}

// async global->LDS, 16B per lane, dest = uniform base + lane*16
#define GLOAD_LDS16(g, l)                                              \
  __builtin_amdgcn_global_load_lds(                                    \
      (const __attribute__((address_space(1))) unsigned int*)(g),      \
      (__attribute__((address_space(3))) unsigned int*)(l), 16, 0, 0)

// ------ generic weight repack: OIHW -> bf16 [tap][o(OPAD)][c], bn folded ----
__global__ __launch_bounds__(256) void k_repack_bf(
    const float* __restrict__ w, const float* __restrict__ g,
    u16* __restrict__ out, int Cout, int Cin, int OPAD, int TAPS) {
  int idx = blockIdx.x * 256 + threadIdx.x;
  int total = TAPS * Cin * OPAD;
  if (idx >= total) return;
  int c = idx % Cin;
  int o = (idx / Cin) % OPAD;
  int tap = idx / (Cin * OPAD);
  float v = 0.f;
  if (o < Cout) v = w[(o * Cin + c) * TAPS + tap] * g[o] * BN_INV;
  out[idx] = f2bf(v);
}

// ================= tiled implicit-GEMM 3x3 conv, bf16 MFMA ==================
// pad: [B][PADW][PADW][CIN] bf16, zero ring. wb: [9][NOUT][CIN] bf16 (bn folded)
// block = 4 waves, tile = TILE_M px (one row chunk) x NB couts.
// K-steps: 9 taps x CIN/64. LDS A[TILE_M][64], B[NB][64], double-buffered.
// XOR swizzle: 16B slot ^= (row&7) (pre-swizzled global src, swizzled ds_read).
template <int PADW, int CIN, int NOUT, int NB, int TILE_M, int EPI>
__global__ __launch_bounds__(256, 2) void k_conv_mfma(
    const u16* __restrict__ pad, const u16* __restrict__ wb,
    const float* __restrict__ bias, void* __restrict__ outp) {
  constexpr int H = PADW - 2;          // output H == W
  constexpr int NSEG = NOUT / NB;
  constexpr int KQ = CIN / 64;
  constexpr int NSTEPS = 9 * KQ;
  constexpr int WM = TILE_M / 4;       // px per wave
  constexpr int MF = WM / 16;
  constexpr int NF = NB / 16;
  __shared__ alignas(16) u16 As[2][TILE_M * 64];
  __shared__ alignas(16) u16 Bs[2][NB * 64];

  int tid = threadIdx.x, wv = tid >> 6, l = tid & 63;
  int bid = blockIdx.x;
  int ns = (NSEG > 1) ? (bid % NSEG) : 0;
  int row = (NSEG > 1) ? (bid / NSEG) : bid;
  int b = row / H, y = row % H;
  const u16* pbat = pad + (size_t)b * PADW * PADW * CIN;

  auto stage = [&](int t, int bufi) {
    int tap = t / KQ;
    int ch0 = (t % KQ) * 64;
    int ky = tap / 3, kx = tap % 3;
    const u16* arow = pbat + ((size_t)(y + ky) * PADW + kx) * CIN + ch0;
#pragma unroll
    for (int j = 0; j < TILE_M * 8 / 256; ++j) {
      int q = j * 256 + tid;
      int px = q >> 3;
      int sl = (q & 7) ^ (px & 7);
      GLOAD_LDS16(arow + (size_t)px * CIN + sl * 8,
                  (char*)&As[bufi][0] + (size_t)(j * 256 + (tid & ~63)) * 16);
    }
    const u16* brow = wb + ((size_t)tap * NOUT + ns * NB) * CIN + ch0;
#pragma unroll
    for (int j = 0; j < NB * 8 / 256; ++j) {
      int q = j * 256 + tid;
      int co = q >> 3;
      int sl = (q & 7) ^ (co & 7);
      GLOAD_LDS16(brow + (size_t)co * CIN + sl * 8,
                  (char*)&Bs[bufi][0] + (size_t)(j * 256 + (tid & ~63)) * 16);
    }
  };

  f32x4 acc[MF][NF];
#pragma unroll
  for (int m = 0; m < MF; ++m)
#pragma unroll
    for (int n = 0; n < NF; ++n) acc[m][n] = (f32x4){0.f, 0.f, 0.f, 0.f};

  stage(0, 0);
  for (int t = 0; t < NSTEPS; ++t) {
    __syncthreads();
    if (t + 1 < NSTEPS) stage(t + 1, (t + 1) & 1);
    const u16* Ab = &As[t & 1][0];
    const u16* Bb = &Bs[t & 1][0];
    bf16x8 Bf[2][NF];
#pragma unroll
    for (int kf = 0; kf < 2; ++kf)
#pragma unroll
      for (int n = 0; n < NF; ++n) {
        int co = n * 16 + (l & 15);
        int sl = (kf * 4 + (l >> 4)) ^ (co & 7);
        Bf[kf][n] = *(const bf16x8*)((const char*)Bb + co * 128 + sl * 16);
      }
#pragma unroll
    for (int m = 0; m < MF; ++m) {
      int px = wv * WM + m * 16 + (l & 15);
      int s0 = (l >> 4) ^ (px & 7);
      int s1 = (4 + (l >> 4)) ^ (px & 7);
      bf16x8 a0 = *(const bf16x8*)((const char*)Ab + px * 128 + s0 * 16);
      bf16x8 a1 = *(const bf16x8*)((const char*)Ab + px * 128 + s1 * 16);
#pragma unroll
      for (int n = 0; n < NF; ++n) {
        acc[m][n] = __builtin_amdgcn_mfma_f32_16x16x32_bf16(a0, Bf[0][n], acc[m][n], 0, 0, 0);
        acc[m][n] = __builtin_amdgcn_mfma_f32_16x16x32_bf16(a1, Bf[1][n], acc[m][n], 0, 0, 0);
      }
    }
  }

  int ncol = l & 15, rq = l >> 4;
  size_t pixb = ((size_t)b * H + y) * H;
  if (EPI == 0) {  // bf16 NHWC (stride NOUT), bias + relu
    u16* ob = (u16*)outp;
#pragma unroll
    for (int m = 0; m < MF; ++m) {
      int px0 = wv * WM + m * 16 + rq * 4;
#pragma unroll
      for (int n = 0; n < NF; ++n) {
        int o = ns * NB + n * 16 + ncol;
        float be = bias[o];
#pragma unroll
        for (int r = 0; r < 4; ++r)
          ob[(pixb + px0 + r) * NOUT + o] = f2bf(fmaxf(acc[m][n][r] + be, 0.f));
      }
    }
  } else {  // EPI==1: fp32, 25-channel (we), bias only
    float* wkp = (float*)outp;
#pragma unroll
    for (int m = 0; m < MF; ++m) {
      int px0 = wv * WM + m * 16 + rq * 4;
#pragma unroll
      for (int n = 0; n < NF; ++n) {
        int o = n * 16 + ncol;
        if (o < 25) {
          float be = bias[o];
#pragma unroll
          for (int r = 0; r < 4; ++r)
            wkp[(pixb + px0 + r) * 25 + o] = acc[m][n][r] + be;
        }
      }
    }
  }
}

// ---------------- t1 = relu(bn(conv1x1(xh, w1)))  (64ch out, 64x64) ---------
__global__ __launch_bounds__(256) void k_t1(
    const float* __restrict__ xh, const float* __restrict__ w1,
    const float* __restrict__ g, const float* __restrict__ bb,
    float* __restrict__ t1) {
  int t = threadIdx.x;
  int o = t & 63, ps = t >> 6;
  int p0 = blockIdx.x * 16 + ps * 4;  // over B*4096
  const float* ip = xh + (size_t)p0 * 128;
  const float* wp = w1 + o * 128;
  float a0 = 0, a1 = 0, a2 = 0, a3 = 0;
  for (int c = 0; c < 128; ++c) {
    float w = wp[c];
    a0 += w * ip[c];       a1 += w * ip[128 + c];
    a2 += w * ip[256 + c]; a3 += w * ip[384 + c];
  }
  float sc = g[o] * BN_INV, be = bb[o];
  t1[(size_t)(p0 + 0) * 64 + o] = fmaxf(a0 * sc + be, 0.f);
  t1[(size_t)(p0 + 1) * 64 + o] = fmaxf(a1 * sc + be, 0.f);
  t1[(size_t)(p0 + 2) * 64 + o] = fmaxf(a2 * sc + be, 0.f);
  t1[(size_t)(p0 + 3) * 64 + o] = fmaxf(a3 * sc + be, 0.f);
}

// ------ bilinear up 64->128 of t1 (64ch) -> xcat_pad bf16 ch 0..63 ----------
__global__ __launch_bounds__(256) void k_up64_pad(const float* __restrict__ in,
                                                  u16* __restrict__ pad) {
  int t = threadIdx.x;
  int cp = (t & 31) * 2;
  int sub = t >> 5;                  // 8 px/block
  int g = blockIdx.x * 8 + sub;      // B*16384
  int b = g >> 14, pp = g & 16383;
  int oy = pp >> 7, ox = pp & 127;
  const float S = 63.0f / 127.0f;
  float fy = oy * S, fx = ox * S;
  int y0 = (int)fy, x0 = (int)fx;
  int y1 = min(y0 + 1, 63), x1 = min(x0 + 1, 63);
  float wy = fy - y0, wx = fx - x0;
  const float* base = in + (size_t)b * 4096 * 64;
  float2 v00 = *(const float2*)(base + ((y0 << 6) + x0) * 64 + cp);
  float2 v01 = *(const float2*)(base + ((y0 << 6) + x1) * 64 + cp);
  float2 v10 = *(const float2*)(base + ((y1 << 6) + x0) * 64 + cp);
  float2 v11 = *(const float2*)(base + ((y1 << 6) + x1) * 64 + cp);
  float r0 = (v00.x * (1.f - wx) + v01.x * wx) * (1.f - wy) +
             (v10.x * (1.f - wx) + v11.x * wx) * wy;
  float r1 = (v00.y * (1.f - wx) + v01.y * wx) * (1.f - wy) +
             (v10.y * (1.f - wx) + v11.y * wx) * wy;
  ushort2 o2; o2.x = f2bf(r0); o2.y = f2bf(r1);
  *(ushort2*)(pad + ((size_t)(b * 130 + oy + 1) * 130 + ox + 1) * 128 + cp) = o2;
}

// ---------------- SE: channel mean of xl ------------------------------------
__global__ __launch_bounds__(256) void k_semean(const float* __restrict__ xl,
                                                float* __restrict__ gmean) {
  int bid = blockIdx.x;  // B*64
  int b = bid >> 6, chunk = bid & 63;
  int t = threadIdx.x;
  int c = t & 127, sub = t >> 7;
  float s = 0.f;
  const float* base = xl + ((size_t)b * 16384 + chunk * 256) * 128;
  for (int p = sub; p < 256; p += 2) s += base[(size_t)p * 128 + c];
  __shared__ float lds[256];
  lds[t] = s;
  __syncthreads();
  if (t < 128) atomicAdd(&gmean[b * 128 + t], lds[t] + lds[t + 128]);
}

// ---------------- SE MLP + sigmoid + build per-batch effective w2 -----------
__global__ __launch_bounds__(128) void k_semlp(
    const float* __restrict__ gmean, const float* __restrict__ wf1,
    const float* __restrict__ bf1, const float* __restrict__ wf2,
    const float* __restrict__ bf2, const float* __restrict__ w2,
    float* __restrict__ weff) {
  int b = blockIdx.x;
  int t = threadIdx.x;  // 128
  __shared__ float m[128], hid[32], sg[128];
  m[t] = gmean[b * 128 + t] * (1.0f / 16384.0f);
  __syncthreads();
  if (t < 32) {
    float a = 0.f;
    for (int c = 0; c < 128; ++c) a += wf1[t * 128 + c] * m[c];
    hid[t] = fmaxf(a + bf1[t], 0.f);
  }
  __syncthreads();
  {
    float a = 0.f;
    for (int r = 0; r < 32; ++r) a += wf2[t * 32 + r] * hid[r];
    a += bf2[t];
    sg[t] = 1.f / (1.f + expf(-a));
  }
  __syncthreads();
  for (int o = 0; o < 64; ++o) {
    weff[((size_t)b * 64 + o) * 128 + t] =
        w2[o * 256 + t] * sg[t] + w2[o * 256 + 128 + t];
  }
}

// ------ x2 = relu(bn(weff_b . xl)) -> xcat_pad bf16 ch 64..127 ---------------
__global__ __launch_bounds__(256) void k_x2_pad(
    const float* __restrict__ xl, const float* __restrict__ weff,
    const float* __restrict__ g, const float* __restrict__ bb,
    u16* __restrict__ pad) {
  int t = threadIdx.x;
  int o = t & 63, ps = t >> 6;
  int p0 = blockIdx.x * 16 + ps * 4;  // over B*16384
  int b = p0 >> 14;
  int pp = p0 & 16383;
  int y = pp >> 7, x0 = pp & 127;
  const float* ip = xl + (size_t)p0 * 128;
  const float* wp = weff + ((size_t)b * 64 + o) * 128;
  float a0 = 0, a1 = 0, a2 = 0, a3 = 0;
  for (int c = 0; c < 128; ++c) {
    float w = wp[c];
    a0 += w * ip[c];       a1 += w * ip[128 + c];
    a2 += w * ip[256 + c]; a3 += w * ip[384 + c];
  }
  float sc = g[o] * BN_INV, be = bb[o];
  size_t rb = (size_t)(b * 130 + y + 1) * 130;
  pad[(rb + x0 + 1) * 128 + 64 + o] = f2bf(fmaxf(a0 * sc + be, 0.f));
  pad[(rb + x0 + 2) * 128 + 64 + o] = f2bf(fmaxf(a1 * sc + be, 0.f));
  pad[(rb + x0 + 3) * 128 + 64 + o] = f2bf(fmaxf(a2 * sc + be, 0.f));
  pad[(rb + x0 + 4) * 128 + 64 + o] = f2bf(fmaxf(a3 * sc + be, 0.f));
}

// ------ xh fp32 NHWC -> padded bf16 [B][66][66][128] ------------------------
__global__ __launch_bounds__(256) void k_xh2pad(const float* __restrict__ xh,
                                                u16* __restrict__ xhp) {
  int idx = blockIdx.x * 256 + threadIdx.x;  // 4*4096*16
  int c0 = (idx & 15) * 8;
  int p = idx >> 4;
  int b = p >> 12, pp = p & 4095;
  int y = pp >> 6, x = pp & 63;
  const float* s = xh + (size_t)p * 128 + c0;
  ushort8 o;
#pragma unroll
  for (int j = 0; j < 8; ++j) o[j] = f2bf(s[j]);
  *(ushort8*)(xhp + ((size_t)(b * 66 + y + 1) * 66 + (x + 1)) * 128 + c0) = o;
}

// ------ xl fp32 NHWC -> padded bf16 wo1-input ch 128..255 --------------------
__global__ __launch_bounds__(256) void k_xl2pad(const float* __restrict__ xl,
                                                u16* __restrict__ pad) {
  int idx = blockIdx.x * 256 + threadIdx.x;  // 65536 px * 16 groups
  int c0 = (idx & 15) * 8;
  int p = idx >> 4;
  int b = p >> 14, pp = p & 16383;
  int y = pp >> 7, x = pp & 127;
  const float* s = xl + (size_t)p * 128 + c0;
  ushort8 o;
#pragma unroll
  for (int j = 0; j < 8; ++j) o[j] = f2bf(s[j]);
  *(ushort8*)(pad + ((size_t)(b * 130 + y + 1) * 130 + (x + 1)) * 256 + 128 + c0) = o;
}

// ---------------- softmax over 25 channels ----------------------------------
__global__ __launch_bounds__(256) void k_softmax25(float* __restrict__ wk) {
  int g = blockIdx.x * 256 + threadIdx.x;  // B*16384
  float* p = wk + (size_t)g * 25;
  float mx = p[0];
#pragma unroll
  for (int i = 1; i < 25; ++i) mx = fmaxf(mx, p[i]);
  float e[25];
  float s = 0.f;
#pragma unroll
  for (int i = 0; i < 25; ++i) {
    e[i] = expf(p[i] - mx);
    s += e[i];
  }
  float inv = 1.f / s;
#pragma unroll
  for (int i = 0; i < 25; ++i) p[i] = e[i] * inv;
}

// ------ bilinear up 64->128 of xr (bf16,128ch) -> xup bf16 -------------------
__global__ __launch_bounds__(256) void k_up128_bf(
    const u16* __restrict__ in, u16* __restrict__ outb) {
  int t = threadIdx.x;
  int cp = (t & 63) * 2;
  int sub = t >> 6;                  // 4 px/block
  int g = blockIdx.x * 4 + sub;      // B*16384
  int b = g >> 14, pp = g & 16383;
  int oy = pp >> 7, ox = pp & 127;
  const float S = 63.0f / 127.0f;
  float fy = oy * S, fx = ox * S;
  int y0 = (int)fy, x0 = (int)fx;
  int y1 = min(y0 + 1, 63), x1 = min(x0 + 1, 63);
  float wy = fy - y0, wx = fx - x0;
  const u16* base = in + (size_t)b * 4096 * 128;
  const u16* p00 = base + ((y0 << 6) + x0) * 128 + cp;
  const u16* p01 = base + ((y0 << 6) + x1) * 128 + cp;
  const u16* p10 = base + ((y1 << 6) + x0) * 128 + cp;
  const u16* p11 = base + ((y1 << 6) + x1) * 128 + cp;
  ushort2 o2;
  u16 r[2];
#pragma unroll
  for (int j = 0; j < 2; ++j) {
    float top = bf2f(p00[j]) * (1.f - wx) + bf2f(p01[j]) * wx;
    float bot = bf2f(p10[j]) * (1.f - wx) + bf2f(p11[j]) * wx;
    r[j] = f2bf(top * (1.f - wy) + bot * wy);
  }
  o2.x = r[0]; o2.y = r[1];
  *(ushort2*)(outb + (size_t)g * 128 + cp) = o2;
}

// ------ CARAFE reassembly (bf16 in) -> wo1-input pad ch 0..127 ---------------
__global__ __launch_bounds__(256) void k_carafe_bf(
    const u16* __restrict__ xup, const float* __restrict__ wk,
    u16* __restrict__ pad) {
  int t = threadIdx.x;
  int cp = (t & 63) * 2;
  int sub = t >> 6;                  // 4 px/block
  int g = blockIdx.x * 4 + sub;
  int b = g >> 14, pp = g & 16383;
  int y = pp >> 7, x = pp & 127;
  __shared__ float wl[4][25];
  if (t < 100) wl[t / 25][t % 25] = wk[(size_t)(blockIdx.x * 4 + t / 25) * 25 + (t % 25)];
  __syncthreads();
  float a0 = 0.f, a1 = 0.f;
  const u16* base = xup + ((size_t)b << 14) * 128 + cp;
#pragma unroll
  for (int i = 0; i < 5; ++i) {
    int row = y + 2 * i - 4;
    if ((unsigned)row >= 128u) continue;
#pragma unroll
    for (int jj = 0; jj < 5; ++jj) {
      int col = x + 2 * jj - 4;
      if ((unsigned)col >= 128u) continue;
      const u16* q = base + (size_t)((row << 7) + col) * 128;
      float w = wl[sub][i * 5 + jj];
      a0 += w * bf2f(q[0]);
      a1 += w * bf2f(q[1]);
    }
  }
  ushort2 o2; o2.x = f2bf(a0); o2.y = f2bf(a1);
  *(ushort2*)(pad + ((size_t)(b * 130 + y + 1) * 130 + (x + 1)) * 256 + cp) = o2;
}

// ------ wo2 1x1 MFMA: y1 bf16 x [128][128] -> out NCHW fp32, relu ------------
__global__ __launch_bounds__(256) void k_wo2_mfma(
    const u16* __restrict__ y1, const u16* __restrict__ wb,
    const float* __restrict__ bb, float* __restrict__ out) {
  int t = threadIdx.x;
  int wv = t >> 6, l = t & 63;
  int blk = blockIdx.x;  // 1024
  int b = blk >> 8, rr = blk & 255;
  int y = rr >> 1;
  int xseg = (rr & 1) << 6;
  int m0 = xseg + wv * 16;
  int xc = m0 + (l & 15);
  int kg = l >> 4;
  const u16* abase =
      y1 + ((size_t)((b << 14) + (y << 7) + xc)) * 128 + kg * 8;
  const u16* bbase = wb + (size_t)(l & 15) * 128 + kg * 8;
  f32x4 acc[8];
#pragma unroll
  for (int i = 0; i < 8; ++i) acc[i] = (f32x4){0.f, 0.f, 0.f, 0.f};
#pragma unroll
  for (int cc = 0; cc < 4; ++cc) {
    bf16x8 a = *(const bf16x8*)(abase + cc * 32);
#pragma unroll
    for (int nf = 0; nf < 8; ++nf) {
      bf16x8 bfr = *(const bf16x8*)(bbase + nf * 16 * 128 + cc * 32);
      acc[nf] = __builtin_amdgcn_mfma_f32_16x16x32_bf16(a, bfr, acc[nf], 0, 0, 0);
    }
  }
  int prow = m0 + (l >> 4) * 4;
  int ncol = l & 15;
#pragma unroll
  for (int nf = 0; nf < 8; ++nf) {
    int o = nf * 16 + ncol;
    float be = bb[o];
    f32x4 r;
#pragma unroll
    for (int k = 0; k < 4; ++k) r[k] = fmaxf(acc[nf][k] + be, 0.f);
    *(f32x4*)(out + (((size_t)(b * 128 + o) * 128 + y) << 7) + prow) = r;
  }
}

extern "C" void kernel_launch(void* const* d_in, const int* in_sizes, int n_in,
                              void* d_out, int out_size, void* d_ws,
                              size_t ws_size, hipStream_t stream) {
  const float* x_h  = (const float*)d_in[0];
  const float* x_l  = (const float*)d_in[1];
  const float* wr   = (const float*)d_in[2];
  const float* wr_g = (const float*)d_in[3];
  const float* wr_b = (const float*)d_in[4];
  const float* w1   = (const float*)d_in[5];
  const float* w1_g = (const float*)d_in[6];
  const float* w1_b = (const float*)d_in[7];
  const float* w2   = (const float*)d_in[8];
  const float* w2_g = (const float*)d_in[9];
  const float* w2_b = (const float*)d_in[10];
  const float* we   = (const float*)d_in[11];
  const float* we_g = (const float*)d_in[12];
  const float* we_b = (const float*)d_in[13];
  const float* wf1  = (const float*)d_in[14];
  const float* bf1  = (const float*)d_in[15];
  const float* wf2  = (const float*)d_in[16];
  const float* bf2  = (const float*)d_in[17];
  const float* wo1  = (const float*)d_in[18];
  const float* wo1_g= (const float*)d_in[19];
  const float* wo1_b= (const float*)d_in[20];
  const float* wo2  = (const float*)d_in[21];
  const float* wo2_g= (const float*)d_in[22];
  const float* wo2_b= (const float*)d_in[23];
  float* out = (float*)d_out;

  float* ws = (float*)d_ws;
  // layout (f32 offsets), total 20,141,568 f32 = 80.57 MB
  u16* pad      = (u16*)ws;                  // [4][130][130][256] bf16
  u16* xcat_pad = (u16*)(ws + 8652800);      // [4][130][130][128] bf16
  u16* xup      = xcat_pad;                  // reuse after we_mfma
  float* wkb   = ws + 12979200;              // 1,638,400 f32
  float* t1    = ws + 14617600;              // 1,048,576 f32
  u16* xr = (u16*)t1;                        // reuse after up64
  float* y1reg = ws + 15666176;              // 4,194,304 f32 region
  u16* y1     = (u16*)y1reg;                 // 8,388,608 bf16 (late)
  u16* xh_pad = (u16*)y1reg;                 // 2,230,272 bf16 (early)
  float* gmean = ws + 19860480;              // 512
  float* weff  = gmean + 512;                // 32,768
  u16* wr_bf = (u16*)(weff + 32768);         // 147,456 bf16
  u16* we_bf = (u16*)(weff + 32768 + 73728); // 36,864 bf16
  u16* wo1bf = (u16*)(weff + 32768 + 73728 + 18432);           // 294,912 bf16
  u16* wo2bf = (u16*)(weff + 32768 + 73728 + 18432 + 147456);  // 16,384 bf16

  hipMemsetAsync(gmean, 0, 512 * sizeof(float), stream);
  hipMemsetAsync(pad, 0, (size_t)4 * 130 * 130 * 256 * 2, stream);
  hipMemsetAsync(xcat_pad, 0, (size_t)4 * 130 * 130 * 128 * 2, stream);
  hipMemsetAsync(xh_pad, 0, (size_t)4 * 66 * 66 * 128 * 2, stream);

  k_repack_bf<<<576, 256, 0, stream>>>(wr, wr_g, wr_bf, 128, 128, 128, 9);
  k_repack_bf<<<144, 256, 0, stream>>>(we, we_g, we_bf, 25, 128, 32, 9);
  k_repack_bf<<<1152, 256, 0, stream>>>(wo1, wo1_g, wo1bf, 128, 256, 128, 9);
  k_repack_bf<<<64, 256, 0, stream>>>(wo2, wo2_g, wo2bf, 128, 128, 128, 1);

  k_t1<<<1024, 256, 0, stream>>>(x_h, w1, w1_g, w1_b, t1);
  k_up64_pad<<<8192, 256, 0, stream>>>(t1, xcat_pad);          // ch 0..63
  k_semean<<<256, 256, 0, stream>>>(x_l, gmean);
  k_semlp<<<4, 128, 0, stream>>>(gmean, wf1, bf1, wf2, bf2, w2, weff);
  k_x2_pad<<<4096, 256, 0, stream>>>(x_l, weff, w2_g, w2_b, xcat_pad);  // ch 64..127
  k_xh2pad<<<1024, 256, 0, stream>>>(x_h, xh_pad);
  k_xl2pad<<<4096, 256, 0, stream>>>(x_l, pad);

  // we: PADW=130, CIN=128, NOUT(pad)=32, NB=32, TILE_M=128, EPI=1 (fp32, 25ch)
  k_conv_mfma<130, 128, 32, 32, 128, 1><<<512, 256, 0, stream>>>(
      xcat_pad, we_bf, we_b, wkb);
  k_softmax25<<<256, 256, 0, stream>>>(wkb);
  // wr: PADW=66, CIN=128, NOUT=128, NB=64 (2 segs), TILE_M=64, EPI=0 (bf16+relu)
  k_conv_mfma<66, 128, 128, 64, 64, 0><<<512, 256, 0, stream>>>(
      xh_pad, wr_bf, wr_b, xr);
  k_up128_bf<<<16384, 256, 0, stream>>>(xr, xup);              // xcat_pad now dead
  k_carafe_bf<<<16384, 256, 0, stream>>>(xup, wkb, pad);       // X -> pad ch 0..127
  // wo1: PADW=130, CIN=256, NOUT=128, NB=128, TILE_M=128, EPI=0 (bf16+relu)
  k_conv_mfma<130, 256, 128, 128, 128, 0><<<512, 256, 0, stream>>>(
      pad, wo1bf, wo1_b, y1);                                  // xh_pad dead
  k_wo2_mfma<<<1024, 256, 0, stream>>>(y1, wo2bf, wo2_b, out);
}